// Round 9
// baseline (5187.243 us; speedup 1.0000x reference)
//
#include <hip/hip_runtime.h>

typedef __bf16 bf16x8 __attribute__((ext_vector_type(8)));
typedef float f32x4 __attribute__((ext_vector_type(4)));
typedef unsigned short ushort8 __attribute__((ext_vector_type(8)));

#define DEV static __device__ __forceinline__

DEV unsigned short f2bf(float f){
  unsigned int u = __builtin_bit_cast(unsigned int, f);
  u += 0x7fffu + ((u >> 16) & 1u);   // RNE; inputs finite
  return (unsigned short)(u >> 16);
}
DEV float bf2f(unsigned short u){
  return __builtin_bit_cast(float, ((unsigned int)u) << 16);
}
DEV float sigf(float x){ return 1.0f/(1.0f + __expf(-x)); }
DEV float tanhf_fast(float x){
  float ax = fabsf(x);
  float e = __expf(2.0f*ax);
  float r = 1.0f - 2.0f/(e + 1.0f);
  return copysignf(r, x);
}

static constexpr int NN   = 100000;   // nodes
static constexpr int NPAD = 100096;   // 782*128
static constexpr int NE   = 1600000;  // edges
static constexpr int NB   = 3000;     // graphs / batch
static constexpr int BPAD = 3072;     // padded batch (24*128)
static constexpr int TT   = 128;      // seq len
static constexpr int HID  = 640;      // LSTM hidden
static constexpr int SCAN_B = 1024;
static constexpr int NBLK = (NN + SCAN_B - 1)/SCAN_B;   // 98

// ======================= prep kernels =======================
__global__ void cvt_k(const float* __restrict__ s, unsigned short* __restrict__ d, int n){
  int i = blockIdx.x*256 + threadIdx.x; if (i < n) d[i] = f2bf(s[i]);
}
__global__ void transpose_cvt_split_k(const float* __restrict__ s, unsigned short* __restrict__ dh,
                                      unsigned short* __restrict__ dl, int R, int C){
  int i = blockIdx.x*256 + threadIdx.x; if (i >= R*C) return;
  int r = i / C, c = i - r*C;
  float v = s[i];
  unsigned short hi = f2bf(v);
  dh[c*R + r] = hi;
  dl[c*R + r] = f2bf(v - bf2f(hi));
}
// Wc2 row n2 = jt*128 + hc*64 + gate*16 + j15  <->  gate-row n = gate*640 + jt*32 + hc*16 + j15
__global__ void wc2_build_k(const float* __restrict__ whh, const float* __restrict__ wih,
                            unsigned short* __restrict__ wc2){
  int i = blockIdx.x*256 + threadIdx.x; if (i >= 2560*704) return;
  int n2 = i / 704, k = i - n2*704;
  int jt = n2 >> 7, rem = n2 & 127;
  int hc = rem >> 6, gate = (rem >> 4) & 3, j15 = rem & 15;
  int n = gate*640 + jt*32 + hc*16 + j15;
  float v = (k < 640) ? whh[n*640 + k] : wih[n*64 + (k - 640)];
  wc2[i] = f2bf(v);
}
__global__ void add_k(const float* __restrict__ a, const float* __restrict__ b, float* __restrict__ o, int n){
  int i = blockIdx.x*256 + threadIdx.x; if (i < n) o[i] = a[i] + b[i];
}

// ======================= CSR build =======================
__global__ __launch_bounds__(256) void deg_hist_k(const int* __restrict__ dsts, int* __restrict__ deg){
  int e = blockIdx.x*256 + threadIdx.x; if (e < NE) atomicAdd(&deg[dsts[e]], 1);
}
__global__ __launch_bounds__(256) void scan_bsum_k(const int* __restrict__ deg, int* __restrict__ bsum){
  __shared__ int red[4];
  int b = blockIdx.x, tid = threadIdx.x;
  int base = b*SCAN_B + tid*4;
  int s = 0;
  #pragma unroll
  for (int q = 0; q < 4; ++q){ int idx = base + q; s += (idx < NN) ? deg[idx] : 0; }
  #pragma unroll
  for (int m = 1; m < 64; m <<= 1) s += __shfl_xor(s, m);
  if ((tid & 63) == 0) red[tid >> 6] = s;
  __syncthreads();
  if (tid == 0) bsum[b] = red[0] + red[1] + red[2] + red[3];
}
__global__ void scan_off_k(int* __restrict__ bsum){
  if (threadIdx.x == 0){
    int run = 0;
    for (int i = 0; i < NBLK; ++i){ int t = bsum[i]; bsum[i] = run; run += t; }
  }
}
__global__ __launch_bounds__(256) void scan_write_k(const int* __restrict__ deg, const int* __restrict__ bsum,
                                                    int* __restrict__ rowptr, int* __restrict__ cursor){
  __shared__ int tsum[256];
  int b = blockIdx.x, tid = threadIdx.x;
  int base = b*SCAN_B + tid*4;
  int v[4]; int s = 0;
  #pragma unroll
  for (int q = 0; q < 4; ++q){ int idx = base + q; v[q] = (idx < NN) ? deg[idx] : 0; s += v[q]; }
  tsum[tid] = s;
  __syncthreads();
  for (int offt = 1; offt < 256; offt <<= 1){
    int y = (tid >= offt) ? tsum[tid - offt] : 0;
    __syncthreads();
    tsum[tid] += y;
    __syncthreads();
  }
  int run = bsum[b] + tsum[tid] - s;
  #pragma unroll
  for (int q = 0; q < 4; ++q){
    int idx = base + q;
    if (idx < NN){ rowptr[idx] = run; cursor[idx] = run; }
    run += v[q];
  }
  if (b == 0 && tid == 0) rowptr[NN] = NE;
}
__global__ __launch_bounds__(256) void csr_fill_k(const int* __restrict__ srcs, const int* __restrict__ dsts,
                                                  int* __restrict__ cursor, int* __restrict__ eidx){
  int e = blockIdx.x*256 + threadIdx.x; if (e >= NE) return;
  int d = dsts[e];
  int pos = atomicAdd(&cursor[d], 1);
  eidx[pos] = srcs[e];
}

__global__ __launch_bounds__(256) void gbound_k(const int* __restrict__ batch, int* __restrict__ gstart){
  int i = blockIdx.x*256 + threadIdx.x;
  if (i >= NN) return;
  int bi = batch[i];
  int bp = (i == 0) ? -1 : batch[i-1];
  for (int g = bp + 1; g <= bi; ++g) gstart[g] = i;
  if (i == NN-1){
    for (int g = bi + 1; g <= NB; ++g) gstart[g] = NN;
  }
}

// ======================= GIN: gather aggregation =======================
__global__ __launch_bounds__(256) void agg128_k(const int* __restrict__ rowptr, const int* __restrict__ eidx,
    const float* __restrict__ H, float* __restrict__ Z){
  int wid = (blockIdx.x*256 + threadIdx.x) >> 6;
  if (wid >= NN) return;
  int lane = threadIdx.x & 63;
  const float2* Hp = (const float2*)H;
  int n0 = rowptr[wid], n1 = rowptr[wid+1];
  float2 acc = Hp[(size_t)wid*64 + lane];
  int i = n0;
  for (; i + 1 < n1; i += 2){
    int s0 = eidx[i], s1 = eidx[i+1];
    float2 v0 = Hp[(size_t)s0*64 + lane];
    float2 v1 = Hp[(size_t)s1*64 + lane];
    acc.x += v0.x + v1.x; acc.y += v0.y + v1.y;
  }
  if (i < n1){
    float2 v = Hp[(size_t)eidx[i]*64 + lane];
    acc.x += v.x; acc.y += v.y;
  }
  ((float2*)Z)[(size_t)wid*64 + lane] = acc;
}
__global__ __launch_bounds__(256) void agg32_k(const int* __restrict__ rowptr, const int* __restrict__ eidx,
    const float* __restrict__ X, float* __restrict__ Z){
  int r = (blockIdx.x*256 + threadIdx.x) >> 5;
  if (r >= NN) return;
  int l = threadIdx.x & 31;
  int n0 = rowptr[r], n1 = rowptr[r+1];
  float acc = X[(size_t)r*32 + l];
  int i = n0;
  for (; i + 1 < n1; i += 2){
    int s0 = eidx[i], s1 = eidx[i+1];
    acc += X[(size_t)s0*32 + l] + X[(size_t)s1*32 + l];
  }
  if (i < n1) acc += X[(size_t)eidx[i]*32 + l];
  Z[(size_t)r*32 + l] = acc;
}

// ======================= GIN: fused 2-layer MLP (split-precision bf16 MFMA) =======================
template<int KIN>
__global__ __launch_bounds__(256) void gin_mlp_k(const float* __restrict__ Z,
    const unsigned short* __restrict__ W1h, const unsigned short* __restrict__ W1l,
    const unsigned short* __restrict__ W2h, const unsigned short* __restrict__ W2l,
    const float* __restrict__ b1, const float* __restrict__ b2,
    float* __restrict__ Y, float* __restrict__ stats)
{
  constexpr int SA = KIN + 8;
  __shared__ __align__(16) unsigned short Ah[128*136];
  __shared__ __align__(16) unsigned short Al[128*136];
  const int tid = threadIdx.x, lane = tid & 63, w = tid >> 6;
  const int row0 = blockIdx.x * 128;
  const int wr = (w >> 1)*64, wc0 = (w & 1)*64;
  const int l15 = lane & 15, lg = lane >> 4;

  constexpr int CH = KIN/8;
  #pragma unroll
  for (int i = 0; i < (128*CH)/256; ++i){
    int chunk = tid + 256*i;
    int row = chunk / CH, kc = (chunk - row*CH)*8;
    const float* sp = Z + (size_t)(row0 + row)*KIN + kc;
    float4 a0 = *(const float4*)sp;
    float4 a1 = *(const float4*)(sp + 4);
    float vv[8] = {a0.x,a0.y,a0.z,a0.w,a1.x,a1.y,a1.z,a1.w};
    ushort8 vh, vl;
    #pragma unroll
    for (int q=0;q<8;++q){ unsigned short h = f2bf(vv[q]); vh[q]=h; vl[q]=f2bf(vv[q]-bf2f(h)); }
    *(ushort8*)&Ah[row*SA + kc] = vh;
    *(ushort8*)&Al[row*SA + kc] = vl;
  }
  __syncthreads();

  f32x4 acc[4][4];
  #pragma unroll
  for (int i=0;i<4;++i)
    #pragma unroll
    for (int j=0;j<4;++j) acc[i][j] = (f32x4)(0.0f);

  #pragma unroll
  for (int k0 = 0; k0 < KIN; k0 += 32){
    bf16x8 ah[4], al[4], bh[4], bl[4];
    #pragma unroll
    for (int fa=0; fa<4; ++fa){
      ah[fa] = *(const bf16x8*)&Ah[(wr + fa*16 + l15)*SA + k0 + 8*lg];
      al[fa] = *(const bf16x8*)&Al[(wr + fa*16 + l15)*SA + k0 + 8*lg];
    }
    #pragma unroll
    for (int fb=0; fb<4; ++fb){
      bh[fb] = *(const bf16x8*)&W1h[(wc0 + fb*16 + l15)*KIN + k0 + 8*lg];
      bl[fb] = *(const bf16x8*)&W1l[(wc0 + fb*16 + l15)*KIN + k0 + 8*lg];
    }
    #pragma unroll
    for (int fa=0; fa<4; ++fa)
      #pragma unroll
      for (int fb=0; fb<4; ++fb){
        acc[fa][fb] = __builtin_amdgcn_mfma_f32_16x16x32_bf16(ah[fa], bh[fb], acc[fa][fb], 0, 0, 0);
        acc[fa][fb] = __builtin_amdgcn_mfma_f32_16x16x32_bf16(al[fa], bh[fb], acc[fa][fb], 0, 0, 0);
        acc[fa][fb] = __builtin_amdgcn_mfma_f32_16x16x32_bf16(ah[fa], bl[fb], acc[fa][fb], 0, 0, 0);
      }
  }
  __syncthreads();

  {
    float b1v[4];
    #pragma unroll
    for (int fb=0; fb<4; ++fb) b1v[fb] = b1[wc0 + fb*16 + l15];
    #pragma unroll
    for (int fa=0; fa<4; ++fa)
      #pragma unroll
      for (int fb=0; fb<4; ++fb)
        #pragma unroll
        for (int r=0; r<4; ++r){
          float v = fmaxf(acc[fa][fb][r] + b1v[fb], 0.0f);
          unsigned short h = f2bf(v);
          int idx = (wr + fa*16 + lg*4 + r)*136 + (wc0 + fb*16 + l15);
          Ah[idx] = h;
          Al[idx] = f2bf(v - bf2f(h));
        }
  }
  __syncthreads();

  f32x4 acc2[4][4];
  #pragma unroll
  for (int i=0;i<4;++i)
    #pragma unroll
    for (int j=0;j<4;++j) acc2[i][j] = (f32x4)(0.0f);

  #pragma unroll
  for (int k0 = 0; k0 < 128; k0 += 32){
    bf16x8 ah[4], al[4], bh[4], bl[4];
    #pragma unroll
    for (int fa=0; fa<4; ++fa){
      ah[fa] = *(const bf16x8*)&Ah[(wr + fa*16 + l15)*136 + k0 + 8*lg];
      al[fa] = *(const bf16x8*)&Al[(wr + fa*16 + l15)*136 + k0 + 8*lg];
    }
    #pragma unroll
    for (int fb=0; fb<4; ++fb){
      bh[fb] = *(const bf16x8*)&W2h[(wc0 + fb*16 + l15)*128 + k0 + 8*lg];
      bl[fb] = *(const bf16x8*)&W2l[(wc0 + fb*16 + l15)*128 + k0 + 8*lg];
    }
    #pragma unroll
    for (int fa=0; fa<4; ++fa)
      #pragma unroll
      for (int fb=0; fb<4; ++fb){
        acc2[fa][fb] = __builtin_amdgcn_mfma_f32_16x16x32_bf16(ah[fa], bh[fb], acc2[fa][fb], 0, 0, 0);
        acc2[fa][fb] = __builtin_amdgcn_mfma_f32_16x16x32_bf16(al[fa], bh[fb], acc2[fa][fb], 0, 0, 0);
        acc2[fa][fb] = __builtin_amdgcn_mfma_f32_16x16x32_bf16(ah[fa], bl[fb], acc2[fa][fb], 0, 0, 0);
      }
  }

  float b2v[4]; int cc[4];
  #pragma unroll
  for (int fb=0; fb<4; ++fb){ cc[fb] = wc0 + fb*16 + l15; b2v[fb] = b2[cc[fb]]; }
  float ps[4] = {0,0,0,0}, pq[4] = {0,0,0,0};
  #pragma unroll
  for (int fa=0; fa<4; ++fa)
    #pragma unroll
    for (int fb=0; fb<4; ++fb)
      #pragma unroll
      for (int r=0; r<4; ++r){
        int row = row0 + wr + fa*16 + lg*4 + r;
        float v = fmaxf(acc2[fa][fb][r] + b2v[fb], 0.0f);
        if (row < NN){
          Y[(size_t)row*128 + cc[fb]] = v;
          ps[fb] += v; pq[fb] += v*v;
        }
      }
  #pragma unroll
  for (int fb=0; fb<4; ++fb){
    float s = ps[fb]; s += __shfl_xor(s, 16); s += __shfl_xor(s, 32);
    float q = pq[fb]; q += __shfl_xor(q, 16); q += __shfl_xor(q, 32);
    if (lane < 16){ atomicAdd(&stats[cc[fb]], s); atomicAdd(&stats[128 + cc[fb]], q); }
  }
}

// ======================= BN helpers =======================
__global__ void bn_finalize_k(const float* __restrict__ stats, const float* __restrict__ gamma,
                              const float* __restrict__ beta, float* __restrict__ sshift, int C, float invN){
  int c = blockIdx.x*blockDim.x + threadIdx.x; if (c >= C) return;
  float mean = stats[c]*invN;
  float var  = fmaxf(stats[C+c]*invN - mean*mean, 0.0f);
  float inv  = rsqrtf(var + 1e-5f);
  float sc   = gamma[c]*inv;
  sshift[c] = sc; sshift[C+c] = beta[c] - mean*sc;
}

// fused BN apply + per-graph pooling: one wave per graph
__global__ __launch_bounds__(256) void bn_pool_k(const float* __restrict__ Y,
    const float* __restrict__ sshift, const int* __restrict__ gstart,
    float* __restrict__ Hb, float* __restrict__ pool, int layer)
{
  int g = blockIdx.x*4 + (threadIdx.x >> 6);
  if (g >= NB) return;
  int lane = threadIdx.x & 63;
  int c0 = lane << 1;
  float sc0 = sshift[c0],     sc1 = sshift[c0+1];
  float sh0 = sshift[128+c0], sh1 = sshift[128+c0+1];
  int n0 = gstart[g], n1 = gstart[g+1];
  const float2* Yp = (const float2*)Y;
  float2* Hp = (float2*)Hb;
  float2 acc = make_float2(0.f, 0.f);
  for (int r = n0; r < n1; ++r){
    float2 y = Yp[(size_t)r*64 + lane];
    float2 h = make_float2(y.x*sc0 + sh0, y.y*sc1 + sh1);
    Hp[(size_t)r*64 + lane] = h;
    acc.x += h.x; acc.y += h.y;
  }
  ((float2*)pool)[(size_t)g*320 + layer*64 + lane] = acc;
}

// ======================= LSTM =======================
// e2 layout: [t][b][64]
__global__ __launch_bounds__(256) void embed_k(const int* __restrict__ smi,
    const unsigned short* __restrict__ emb_bf, unsigned short* __restrict__ e2){
  int gid = blockIdx.x*256 + threadIdx.x;
  int tb = gid >> 4;
  if (tb >= TT*BPAD) return;
  int t = tb / BPAD, b = tb - t*BPAD;
  int k4 = (gid & 15) << 2;
  uint2 v = make_uint2(0u, 0u);
  if (b < NB){
    int tok = smi[b*TT + t];
    v = *(const uint2*)&emb_bf[tok*64 + k4];
  }
  *(uint2*)&e2[(size_t)tb*64 + k4] = v;
}

// One LSTM step, BARRIER-FREE: each wave owns its A-rows/B-rows in private LDS
// (double-buffered). No __syncthreads in the K-loop — only per-wave lgkmcnt
// ordering. Block = 128 rows x 128 gate-cols; wave = 64 rows x 64 cols (4 gates).
__global__ __launch_bounds__(256) void lstm_step_k(const unsigned short* __restrict__ hprev,
    unsigned short* __restrict__ hnext, float* __restrict__ cbuf,
    const unsigned short* __restrict__ e2, const unsigned short* __restrict__ Wc2,
    const float* __restrict__ biasc, int t, float* __restrict__ hfin)
{
  __shared__ __align__(16) unsigned short Aw[4][2][64*40];
  __shared__ __align__(16) unsigned short Bw[4][2][64*40];
  const int tid = threadIdx.x, lane = tid & 63, w = tid >> 6;
  const int row0 = blockIdx.x * 128;
  const int jt = blockIdx.y;                 // j-tile of 32
  const int l15 = lane & 15, lg = lane >> 4;
  const int wr = (w >> 1)*64, wc0 = (w & 1)*64;

  // per-lane staging: 4 chunks; chunk i -> row = (lane>>2)+16*i, col (lane&3)*8 shorts
  const int srow = lane >> 2, skc = (lane & 3) << 3;
  const unsigned short* Abase = hprev + (size_t)(row0 + wr)*HID;
  const unsigned short* Ebase = e2 + ((size_t)t*BPAD + row0 + wr)*64;
  const unsigned short* Bbase = Wc2 + (size_t)(jt*128 + wc0)*704;

  unsigned short* Amy = &Aw[w][0][0];   // [2][64*40]
  unsigned short* Bmy = &Bw[w][0][0];

  // prologue: stage kk=0 (always h-part)
  #pragma unroll
  for (int i = 0; i < 4; ++i){
    int row = srow + 16*i;
    *(ushort8*)&Amy[row*40 + skc] = *(const ushort8*)&Abase[(size_t)row*HID + skc];
    *(ushort8*)&Bmy[row*40 + skc] = *(const ushort8*)&Bbase[(size_t)row*704 + skc];
  }

  f32x4 acc[4][4];
  #pragma unroll
  for (int i=0;i<4;++i)
    #pragma unroll
    for (int j=0;j<4;++j) acc[i][j] = (f32x4)(0.0f);

  int p = 0;
  for (int kk = 0; kk < 22; ++kk){
    ushort8 va[4], vb[4];
    const int k1 = (kk+1)*32;
    if (kk < 21){
      #pragma unroll
      for (int i = 0; i < 4; ++i){
        int row = srow + 16*i;
        va[i] = (k1 < 640) ? *(const ushort8*)&Abase[(size_t)row*HID + k1 + skc]
                           : *(const ushort8*)&Ebase[(size_t)row*64 + (k1 - 640) + skc];
        vb[i] = *(const ushort8*)&Bbase[(size_t)row*704 + k1 + skc];
      }
    }
    const unsigned short* Ap = Amy + p*(64*40);
    const unsigned short* Bp = Bmy + p*(64*40);
    bf16x8 a[4], b[4];
    #pragma unroll
    for (int fa=0; fa<4; ++fa) a[fa] = *(const bf16x8*)&Ap[(fa*16 + l15)*40 + 8*lg];
    #pragma unroll
    for (int fb=0; fb<4; ++fb) b[fb] = *(const bf16x8*)&Bp[(fb*16 + l15)*40 + 8*lg];
    __builtin_amdgcn_s_setprio(1);
    #pragma unroll
    for (int fa=0; fa<4; ++fa)
      #pragma unroll
      for (int fb=0; fb<4; ++fb)
        acc[fa][fb] = __builtin_amdgcn_mfma_f32_16x16x32_bf16(a[fa], b[fb], acc[fa][fb], 0, 0, 0);
    __builtin_amdgcn_s_setprio(0);
    if (kk < 21){
      unsigned short* An = Amy + (p^1)*(64*40);
      unsigned short* Bn = Bmy + (p^1)*(64*40);
      #pragma unroll
      for (int i = 0; i < 4; ++i){
        int row = srow + 16*i;
        *(ushort8*)&An[row*40 + skc] = va[i];
        *(ushort8*)&Bn[row*40 + skc] = vb[i];
      }
    }
    p ^= 1;
  }

  // epilogue: fragment fb == gate; j = jt*32 + (w&1)*16 + l15
  const int j = jt*32 + (w & 1)*16 + l15;
  float bi = biasc[j], bf_ = biasc[640+j], bg = biasc[1280+j], bo = biasc[1920+j];
  #pragma unroll
  for (int fa=0; fa<4; ++fa){
    #pragma unroll
    for (int r=0; r<4; ++r){
      int br = row0 + wr + fa*16 + lg*4 + r;
      float iv = acc[fa][0][r] + bi;
      float fv = acc[fa][1][r] + bf_;
      float gv = acc[fa][2][r] + bg;
      float ov = acc[fa][3][r] + bo;
      size_t idx = (size_t)br*HID + j;
      float co = cbuf[idx];
      float cn = sigf(fv)*co + sigf(iv)*tanhf_fast(gv);
      cbuf[idx] = cn;
      float hv = sigf(ov)*tanhf_fast(cn);
      hnext[idx] = f2bf(hv);
      if (hfin) hfin[idx] = hv;
    }
  }
}

// ======================= split-precision GEMM (heads) =======================
template<int DO_STATS>
__global__ __launch_bounds__(256) void gemm_split_k(const float* __restrict__ A,
    const unsigned short* __restrict__ Bh, const unsigned short* __restrict__ Bl,
    const float* __restrict__ bias, float* __restrict__ outp, float* __restrict__ stats,
    int Mvalid, int Nc, int K)
{
  __shared__ __align__(16) unsigned short Ah[128*40];
  __shared__ __align__(16) unsigned short Al[128*40];
  const int tid = threadIdx.x, lane = tid & 63, w = tid >> 6;
  const int row0 = blockIdx.x * 128, col0 = blockIdx.y * 128;
  const int wr = (w >> 1)*64, wc0 = (w & 1)*64;
  const int l15 = lane & 15, lg = lane >> 4;

  f32x4 acc[4][4];
  #pragma unroll
  for (int i=0;i<4;++i)
    #pragma unroll
    for (int j=0;j<4;++j) acc[i][j] = (f32x4)(0.0f);

  for (int k0 = 0; k0 < K; k0 += 32){
    #pragma unroll
    for (int i=0;i<2;++i){
      int chunk = tid + 256*i;
      int row = chunk >> 2, kc = (chunk & 3) << 3;
      const float* sp = A + (size_t)(row0+row)*K + k0 + kc;
      float4 a0 = *(const float4*)sp;
      float4 a1 = *(const float4*)(sp + 4);
      float vv[8] = {a0.x,a0.y,a0.z,a0.w,a1.x,a1.y,a1.z,a1.w};
      ushort8 vh, vl;
      #pragma unroll
      for (int q=0;q<8;++q){ unsigned short h = f2bf(vv[q]); vh[q]=h; vl[q]=f2bf(vv[q]-bf2f(h)); }
      *(ushort8*)&Ah[row*40 + kc] = vh;
      *(ushort8*)&Al[row*40 + kc] = vl;
    }
    __syncthreads();
    bf16x8 ah[4], al[4], bh[4], bl[4];
    #pragma unroll
    for (int fa=0; fa<4; ++fa){
      ah[fa] = *(const bf16x8*)&Ah[(wr + fa*16 + l15)*40 + 8*lg];
      al[fa] = *(const bf16x8*)&Al[(wr + fa*16 + l15)*40 + 8*lg];
    }
    #pragma unroll
    for (int fb=0; fb<4; ++fb){
      bh[fb] = *(const bf16x8*)&Bh[(size_t)(col0 + wc0 + fb*16 + l15)*K + k0 + 8*lg];
      bl[fb] = *(const bf16x8*)&Bl[(size_t)(col0 + wc0 + fb*16 + l15)*K + k0 + 8*lg];
    }
    #pragma unroll
    for (int fa=0; fa<4; ++fa)
      #pragma unroll
      for (int fb=0; fb<4; ++fb){
        acc[fa][fb] = __builtin_amdgcn_mfma_f32_16x16x32_bf16(ah[fa], bh[fb], acc[fa][fb], 0, 0, 0);
        acc[fa][fb] = __builtin_amdgcn_mfma_f32_16x16x32_bf16(al[fa], bh[fb], acc[fa][fb], 0, 0, 0);
        acc[fa][fb] = __builtin_amdgcn_mfma_f32_16x16x32_bf16(ah[fa], bl[fb], acc[fa][fb], 0, 0, 0);
      }
    __syncthreads();
  }

  float bv[4]; int cc[4];
  #pragma unroll
  for (int fb=0; fb<4; ++fb){ cc[fb] = col0 + wc0 + fb*16 + l15; bv[fb] = bias ? bias[cc[fb]] : 0.0f; }
  float ps[4] = {0,0,0,0}, pq[4] = {0,0,0,0};
  #pragma unroll
  for (int fa=0; fa<4; ++fa)
    #pragma unroll
    for (int fb=0; fb<4; ++fb)
      #pragma unroll
      for (int r=0; r<4; ++r){
        int row = row0 + wr + fa*16 + lg*4 + r;
        float v = acc[fa][fb][r] + bv[fb];
        if (row < Mvalid){
          outp[(size_t)row*Nc + cc[fb]] = v;
          if (DO_STATS){ ps[fb] += v; pq[fb] += v*v; }
        }
      }
  if (DO_STATS){
    #pragma unroll
    for (int fb=0; fb<4; ++fb){
      float s = ps[fb]; s += __shfl_xor(s, 16); s += __shfl_xor(s, 32);
      float q = pq[fb]; q += __shfl_xor(q, 16); q += __shfl_xor(q, 32);
      if (lane < 16){ atomicAdd(&stats[cc[fb]], s); atomicAdd(&stats[Nc + cc[fb]], q); }
    }
  }
}

__global__ __launch_bounds__(256) void bn_apply_head_k(const float* __restrict__ Zpre,
    const float* __restrict__ sshift, float* __restrict__ z1f){
  int gid = blockIdx.x*256 + threadIdx.x;
  int r = gid >> 7;
  if (r >= BPAD) return;
  int c0 = (gid & 127) << 2;
  float4 o = make_float4(0.f,0.f,0.f,0.f);
  if (r < NB){
    float4 v = *(const float4*)&Zpre[(size_t)r*512 + c0];
    o.x = fmaxf(v.x*sshift[c0+0] + sshift[512+c0+0], 0.0f);
    o.y = fmaxf(v.y*sshift[c0+1] + sshift[512+c0+1], 0.0f);
    o.z = fmaxf(v.z*sshift[c0+2] + sshift[512+c0+2], 0.0f);
    o.w = fmaxf(v.w*sshift[c0+3] + sshift[512+c0+3], 0.0f);
  }
  *(float4*)&z1f[(size_t)r*512 + c0] = o;
}

__global__ __launch_bounds__(256) void rownorm_k(const float* __restrict__ in, float* __restrict__ outp){
  int r = blockIdx.x;
  const float* p = in + (size_t)r*768;
  float ss = 0.0f;
  #pragma unroll
  for (int i = 0; i < 3; ++i){ float v = p[threadIdx.x + 256*i]; ss += v*v; }
  #pragma unroll
  for (int m = 1; m < 64; m <<= 1) ss += __shfl_xor(ss, m);
  __shared__ float red[4];
  if ((threadIdx.x & 63) == 0) red[threadIdx.x >> 6] = ss;
  __syncthreads();
  float tot = red[0] + red[1] + red[2] + red[3];
  float inv = 1.0f / fmaxf(sqrtf(tot), 1e-12f);
  float* q = outp + (size_t)r*768;
  #pragma unroll
  for (int i = 0; i < 3; ++i) q[threadIdx.x + 256*i] = p[threadIdx.x + 256*i]*inv;
}

// ======================= launcher =======================
static inline int cdiv(long a, long b){ return (int)((a + b - 1)/b); }

extern "C" void kernel_launch(void* const* d_in, const int* in_sizes, int n_in,
                              void* d_out, int out_size, void* d_ws, size_t ws_size,
                              hipStream_t stream)
{
  const float* x        = (const float*)d_in[0];
  const int*   edges    = (const int*)d_in[1];
  const int*   batch    = (const int*)d_in[2];
  const int*   smi      = (const int*)d_in[3];
  const float* gin0_w1  = (const float*)d_in[4];
  const float* gin0_b1  = (const float*)d_in[5];
  const float* gin0_w2  = (const float*)d_in[6];
  const float* gin0_b2  = (const float*)d_in[7];
  const float* ginr_w1  = (const float*)d_in[8];
  const float* ginr_b1  = (const float*)d_in[9];
  const float* ginr_w2  = (const float*)d_in[10];
  const float* ginr_b2  = (const float*)d_in[11];
  const float* bn_gamma = (const float*)d_in[12];
  const float* bn_beta  = (const float*)d_in[13];
  const float* emb      = (const float*)d_in[14];
  const float* w_ih     = (const float*)d_in[15];
  const float* w_hh     = (const float*)d_in[16];
  const float* b_ih     = (const float*)d_in[17];
  const float* b_hh     = (const float*)d_in[18];
  const float* g_w1     = (const float*)d_in[19];
  const float* g_b1     = (const float*)d_in[20];
  const float* g_bng    = (const float*)d_in[21];
  const float* g_bnb    = (const float*)d_in[22];
  const float* g_w2     = (const float*)d_in[23];
  float* outp = (float*)d_out;
  const int* srcs = edges;
  const int* dsts = edges + NE;

  char* base = (char*)d_ws;
  size_t off = 0;
  auto carve = [&](size_t bytes)->char*{ char* p = base + off; off += (bytes + 255) & ~(size_t)255; return p; };
  float* z_gin = (float*)carve((size_t)NPAD*128*4);      // reused for head temps
  float* y_gin = (float*)carve((size_t)NPAD*128*4);      // reused for e2
  float* h_gin = (float*)carve((size_t)NPAD*128*4);      // reused for LSTM state
  float* pool  = (float*)carve((size_t)BPAD*HID*4);
  unsigned short* Wc2    = (unsigned short*)carve((size_t)2560*704*2);
  float*          biasc  = (float*)carve(2560*4);
  unsigned short* emb_bf = (unsigned short*)carve(4096*2);
  unsigned short* w1t0h  = (unsigned short*)carve(128*32*2);
  unsigned short* w1t0l  = (unsigned short*)carve(128*32*2);
  unsigned short* w2t0h  = (unsigned short*)carve(128*128*2);
  unsigned short* w2t0l  = (unsigned short*)carve(128*128*2);
  unsigned short* w1trh  = (unsigned short*)carve(4*16384*2);
  unsigned short* w1trl  = (unsigned short*)carve(4*16384*2);
  unsigned short* w2trh  = (unsigned short*)carve(4*16384*2);
  unsigned short* w2trl  = (unsigned short*)carve(4*16384*2);
  unsigned short* gw1th  = (unsigned short*)carve(512*640*2);
  unsigned short* gw1tl  = (unsigned short*)carve(512*640*2);
  unsigned short* gw2th  = (unsigned short*)carve(768*512*2);
  unsigned short* gw2tl  = (unsigned short*)carve(768*512*2);
  float* stats  = (float*)carve(1024*4);
  float* sshift = (float*)carve(1024*4);
  int* deg    = (int*)carve((size_t)NN*4);
  int* cursor = (int*)carve((size_t)NN*4);
  int* rowptr = (int*)carve((size_t)(NN+1)*4);
  int* bsum   = (int*)carve(512);
  int* eidx   = (int*)carve((size_t)NE*4);
  int* gstart = (int*)carve((size_t)(NB+1)*4);

  // aliases (regions free at the time of reuse)
  unsigned short* e2     = (unsigned short*)y_gin;                       // [t][b][64], 50.3 MB
  unsigned short* h_a    = (unsigned short*)h_gin;
  unsigned short* h_b    = h_a + (size_t)BPAD*HID;
  float*          c_buf  = (float*)(h_b + (size_t)BPAD*HID);
  float*          hfin   = c_buf + (size_t)BPAD*HID;                     // fp32 final h
  float*          z1pre  = (float*)z_gin;
  float*          z1f    = z1pre + (size_t)BPAD*512;
  float*          outtmp = z1f + (size_t)BPAD*512;

  // ---- prep (weight conversions) ----
  wc2_build_k<<<cdiv((long)2560*704,256),256,0,stream>>>(w_hh, w_ih, Wc2);
  add_k<<<cdiv(2560,256),256,0,stream>>>(b_ih, b_hh, biasc, 2560);
  cvt_k<<<cdiv(4096,256),256,0,stream>>>(emb, emb_bf, 4096);
  transpose_cvt_split_k<<<cdiv(32*128,256),256,0,stream>>>(gin0_w1, w1t0h, w1t0l, 32, 128);
  transpose_cvt_split_k<<<cdiv(16384,256),256,0,stream>>>(gin0_w2, w2t0h, w2t0l, 128, 128);
  for (int i = 0; i < 4; ++i){
    transpose_cvt_split_k<<<cdiv(16384,256),256,0,stream>>>(ginr_w1 + (size_t)i*16384, w1trh + (size_t)i*16384, w1trl + (size_t)i*16384, 128, 128);
    transpose_cvt_split_k<<<cdiv(16384,256),256,0,stream>>>(ginr_w2 + (size_t)i*16384, w2trh + (size_t)i*16384, w2trl + (size_t)i*16384, 128, 128);
  }
  transpose_cvt_split_k<<<cdiv(640*512,256),256,0,stream>>>(g_w1, gw1th, gw1tl, 640, 512);
  transpose_cvt_split_k<<<cdiv(512*768,256),256,0,stream>>>(g_w2, gw2th, gw2tl, 512, 768);

  // ---- CSR + graph bounds (once) ----
  hipMemsetAsync(deg, 0, (size_t)NN*4, stream);
  deg_hist_k<<<cdiv(NE,256),256,0,stream>>>(dsts, deg);
  scan_bsum_k<<<NBLK,256,0,stream>>>(deg, bsum);
  scan_off_k<<<1,64,0,stream>>>(bsum);
  scan_write_k<<<NBLK,256,0,stream>>>(deg, bsum, rowptr, cursor);
  csr_fill_k<<<cdiv(NE,256),256,0,stream>>>(srcs, dsts, cursor, eidx);
  gbound_k<<<cdiv(NN,256),256,0,stream>>>(batch, gstart);

  // ---- GIN encoder ----
  for (int l = 0; l < 5; ++l){
    hipMemsetAsync(stats, 0, 1024*4, stream);
    if (l == 0)
      agg32_k<<<cdiv((long)NN*32,256),256,0,stream>>>(rowptr, eidx, x, z_gin);
    else
      agg128_k<<<cdiv((long)NN*64,256),256,0,stream>>>(rowptr, eidx, h_gin, z_gin);
    if (l == 0)
      gin_mlp_k<32><<<NPAD/128,256,0,stream>>>(z_gin, w1t0h, w1t0l, w2t0h, w2t0l, gin0_b1, gin0_b2, y_gin, stats);
    else
      gin_mlp_k<128><<<NPAD/128,256,0,stream>>>(z_gin, w1trh + (size_t)(l-1)*16384, w1trl + (size_t)(l-1)*16384,
                                                w2trh + (size_t)(l-1)*16384, w2trl + (size_t)(l-1)*16384,
                                                ginr_b1 + (l-1)*128, ginr_b2 + (l-1)*128, y_gin, stats);
    bn_finalize_k<<<1,128,0,stream>>>(stats, bn_gamma + l*128, bn_beta + l*128, sshift, 128, 1.0f/NN);
    bn_pool_k<<<cdiv(NB,4),256,0,stream>>>(y_gin, sshift, gstart, h_gin, pool, l);
  }

  // ---- LSTM (per-step launches; barrier-free wave-private kernel) ----
  embed_k<<<cdiv((long)TT*BPAD*16,256),256,0,stream>>>(smi, emb_bf, e2);
  hipMemsetAsync(h_a, 0, (size_t)BPAD*HID*2, stream);
  hipMemsetAsync(c_buf, 0, (size_t)BPAD*HID*4, stream);
  for (int t = 0; t < TT; ++t){
    const unsigned short* hin = (t & 1) ? h_b : h_a;
    unsigned short* hout      = (t & 1) ? h_a : h_b;
    lstm_step_k<<<dim3(BPAD/128, 20),256,0,stream>>>(hin, hout, c_buf, e2, Wc2, biasc, t,
                                                     (t == TT-1) ? hfin : nullptr);
  }

  // ---- heads ----
  const float* headAf[2] = { pool, hfin };
  for (int hd = 0; hd < 2; ++hd){
    hipMemsetAsync(stats, 0, 1024*4, stream);
    gemm_split_k<1><<<dim3(BPAD/128, 4),256,0,stream>>>(headAf[hd], gw1th, gw1tl, g_b1, z1pre, stats, NB, 512, 640);
    bn_finalize_k<<<2,256,0,stream>>>(stats, g_bng, g_bnb, sshift, 512, 1.0f/NB);
    bn_apply_head_k<<<cdiv((long)BPAD*128,256),256,0,stream>>>(z1pre, sshift, z1f);
    gemm_split_k<0><<<dim3(BPAD/128, 6),256,0,stream>>>(z1f, gw2th, gw2tl, nullptr, outtmp, nullptr, NB, 768, 512);
    rownorm_k<<<NB,256,0,stream>>>(outtmp, outp + (size_t)hd*NB*768);
  }
}

// Round 10
// 4384.344 us; speedup vs baseline: 1.1831x; 1.1831x over previous
//
#include <hip/hip_runtime.h>

typedef __bf16 bf16x8 __attribute__((ext_vector_type(8)));
typedef float f32x4 __attribute__((ext_vector_type(4)));
typedef unsigned short ushort8 __attribute__((ext_vector_type(8)));

#define DEV static __device__ __forceinline__

DEV unsigned short f2bf(float f){
  unsigned int u = __builtin_bit_cast(unsigned int, f);
  u += 0x7fffu + ((u >> 16) & 1u);   // RNE; inputs finite
  return (unsigned short)(u >> 16);
}
DEV float bf2f(unsigned short u){
  return __builtin_bit_cast(float, ((unsigned int)u) << 16);
}
DEV float sigf(float x){ return 1.0f/(1.0f + __expf(-x)); }
DEV float tanhf_fast(float x){
  float ax = fabsf(x);
  float e = __expf(2.0f*ax);
  float r = 1.0f - 2.0f/(e + 1.0f);
  return copysignf(r, x);
}

static constexpr int NN   = 100000;   // nodes
static constexpr int NPAD = 100096;   // 782*128
static constexpr int NE   = 1600000;  // edges
static constexpr int NB   = 3000;     // graphs / batch
static constexpr int BPAD = 3072;     // padded batch (24*128)
static constexpr int TT   = 128;      // seq len
static constexpr int HID  = 640;      // LSTM hidden
static constexpr int SCAN_B = 1024;
static constexpr int NBLK = (NN + SCAN_B - 1)/SCAN_B;   // 98

// ======================= prep kernels =======================
__global__ void cvt_k(const float* __restrict__ s, unsigned short* __restrict__ d, int n){
  int i = blockIdx.x*256 + threadIdx.x; if (i < n) d[i] = f2bf(s[i]);
}
__global__ void transpose_cvt_split_k(const float* __restrict__ s, unsigned short* __restrict__ dh,
                                      unsigned short* __restrict__ dl, int R, int C){
  int i = blockIdx.x*256 + threadIdx.x; if (i >= R*C) return;
  int r = i / C, c = i - r*C;
  float v = s[i];
  unsigned short hi = f2bf(v);
  dh[c*R + r] = hi;
  dl[c*R + r] = f2bf(v - bf2f(hi));
}
// Wc2 row n2 = jt*128 + hc*64 + gate*16 + j15  <->  gate-row n = gate*640 + jt*32 + hc*16 + j15
__global__ void wc2_build_k(const float* __restrict__ whh, const float* __restrict__ wih,
                            unsigned short* __restrict__ wc2){
  int i = blockIdx.x*256 + threadIdx.x; if (i >= 2560*704) return;
  int n2 = i / 704, k = i - n2*704;
  int jt = n2 >> 7, rem = n2 & 127;
  int hc = rem >> 6, gate = (rem >> 4) & 3, j15 = rem & 15;
  int n = gate*640 + jt*32 + hc*16 + j15;
  float v = (k < 640) ? whh[n*640 + k] : wih[n*64 + (k - 640)];
  wc2[i] = f2bf(v);
}
__global__ void add_k(const float* __restrict__ a, const float* __restrict__ b, float* __restrict__ o, int n){
  int i = blockIdx.x*256 + threadIdx.x; if (i < n) o[i] = a[i] + b[i];
}

// ======================= CSR build =======================
__global__ __launch_bounds__(256) void deg_hist_k(const int* __restrict__ dsts, int* __restrict__ deg){
  int e = blockIdx.x*256 + threadIdx.x; if (e < NE) atomicAdd(&deg[dsts[e]], 1);
}
__global__ __launch_bounds__(256) void scan_bsum_k(const int* __restrict__ deg, int* __restrict__ bsum){
  __shared__ int red[4];
  int b = blockIdx.x, tid = threadIdx.x;
  int base = b*SCAN_B + tid*4;
  int s = 0;
  #pragma unroll
  for (int q = 0; q < 4; ++q){ int idx = base + q; s += (idx < NN) ? deg[idx] : 0; }
  #pragma unroll
  for (int m = 1; m < 64; m <<= 1) s += __shfl_xor(s, m);
  if ((tid & 63) == 0) red[tid >> 6] = s;
  __syncthreads();
  if (tid == 0) bsum[b] = red[0] + red[1] + red[2] + red[3];
}
__global__ void scan_off_k(int* __restrict__ bsum){
  if (threadIdx.x == 0){
    int run = 0;
    for (int i = 0; i < NBLK; ++i){ int t = bsum[i]; bsum[i] = run; run += t; }
  }
}
__global__ __launch_bounds__(256) void scan_write_k(const int* __restrict__ deg, const int* __restrict__ bsum,
                                                    int* __restrict__ rowptr, int* __restrict__ cursor){
  __shared__ int tsum[256];
  int b = blockIdx.x, tid = threadIdx.x;
  int base = b*SCAN_B + tid*4;
  int v[4]; int s = 0;
  #pragma unroll
  for (int q = 0; q < 4; ++q){ int idx = base + q; v[q] = (idx < NN) ? deg[idx] : 0; s += v[q]; }
  tsum[tid] = s;
  __syncthreads();
  for (int offt = 1; offt < 256; offt <<= 1){
    int y = (tid >= offt) ? tsum[tid - offt] : 0;
    __syncthreads();
    tsum[tid] += y;
    __syncthreads();
  }
  int run = bsum[b] + tsum[tid] - s;
  #pragma unroll
  for (int q = 0; q < 4; ++q){
    int idx = base + q;
    if (idx < NN){ rowptr[idx] = run; cursor[idx] = run; }
    run += v[q];
  }
  if (b == 0 && tid == 0) rowptr[NN] = NE;
}
__global__ __launch_bounds__(256) void csr_fill_k(const int* __restrict__ srcs, const int* __restrict__ dsts,
                                                  int* __restrict__ cursor, int* __restrict__ eidx){
  int e = blockIdx.x*256 + threadIdx.x; if (e >= NE) return;
  int d = dsts[e];
  int pos = atomicAdd(&cursor[d], 1);
  eidx[pos] = srcs[e];
}

__global__ __launch_bounds__(256) void gbound_k(const int* __restrict__ batch, int* __restrict__ gstart){
  int i = blockIdx.x*256 + threadIdx.x;
  if (i >= NN) return;
  int bi = batch[i];
  int bp = (i == 0) ? -1 : batch[i-1];
  for (int g = bp + 1; g <= bi; ++g) gstart[g] = i;
  if (i == NN-1){
    for (int g = bi + 1; g <= NB; ++g) gstart[g] = NN;
  }
}

// ======================= GIN: gather aggregation =======================
__global__ __launch_bounds__(256) void agg128_k(const int* __restrict__ rowptr, const int* __restrict__ eidx,
    const float* __restrict__ H, float* __restrict__ Z){
  int wid = (blockIdx.x*256 + threadIdx.x) >> 6;
  if (wid >= NN) return;
  int lane = threadIdx.x & 63;
  const float2* Hp = (const float2*)H;
  int n0 = rowptr[wid], n1 = rowptr[wid+1];
  float2 acc = Hp[(size_t)wid*64 + lane];
  int i = n0;
  for (; i + 1 < n1; i += 2){
    int s0 = eidx[i], s1 = eidx[i+1];
    float2 v0 = Hp[(size_t)s0*64 + lane];
    float2 v1 = Hp[(size_t)s1*64 + lane];
    acc.x += v0.x + v1.x; acc.y += v0.y + v1.y;
  }
  if (i < n1){
    float2 v = Hp[(size_t)eidx[i]*64 + lane];
    acc.x += v.x; acc.y += v.y;
  }
  ((float2*)Z)[(size_t)wid*64 + lane] = acc;
}
__global__ __launch_bounds__(256) void agg32_k(const int* __restrict__ rowptr, const int* __restrict__ eidx,
    const float* __restrict__ X, float* __restrict__ Z){
  int r = (blockIdx.x*256 + threadIdx.x) >> 5;
  if (r >= NN) return;
  int l = threadIdx.x & 31;
  int n0 = rowptr[r], n1 = rowptr[r+1];
  float acc = X[(size_t)r*32 + l];
  int i = n0;
  for (; i + 1 < n1; i += 2){
    int s0 = eidx[i], s1 = eidx[i+1];
    acc += X[(size_t)s0*32 + l] + X[(size_t)s1*32 + l];
  }
  if (i < n1) acc += X[(size_t)eidx[i]*32 + l];
  Z[(size_t)r*32 + l] = acc;
}

// ======================= GIN: fused 2-layer MLP (split-precision bf16 MFMA) =======================
template<int KIN>
__global__ __launch_bounds__(256) void gin_mlp_k(const float* __restrict__ Z,
    const unsigned short* __restrict__ W1h, const unsigned short* __restrict__ W1l,
    const unsigned short* __restrict__ W2h, const unsigned short* __restrict__ W2l,
    const float* __restrict__ b1, const float* __restrict__ b2,
    float* __restrict__ Y, float* __restrict__ stats)
{
  constexpr int SA = KIN + 8;
  __shared__ __align__(16) unsigned short Ah[128*136];
  __shared__ __align__(16) unsigned short Al[128*136];
  const int tid = threadIdx.x, lane = tid & 63, w = tid >> 6;
  const int row0 = blockIdx.x * 128;
  const int wr = (w >> 1)*64, wc0 = (w & 1)*64;
  const int l15 = lane & 15, lg = lane >> 4;

  constexpr int CH = KIN/8;
  #pragma unroll
  for (int i = 0; i < (128*CH)/256; ++i){
    int chunk = tid + 256*i;
    int row = chunk / CH, kc = (chunk - row*CH)*8;
    const float* sp = Z + (size_t)(row0 + row)*KIN + kc;
    float4 a0 = *(const float4*)sp;
    float4 a1 = *(const float4*)(sp + 4);
    float vv[8] = {a0.x,a0.y,a0.z,a0.w,a1.x,a1.y,a1.z,a1.w};
    ushort8 vh, vl;
    #pragma unroll
    for (int q=0;q<8;++q){ unsigned short h = f2bf(vv[q]); vh[q]=h; vl[q]=f2bf(vv[q]-bf2f(h)); }
    *(ushort8*)&Ah[row*SA + kc] = vh;
    *(ushort8*)&Al[row*SA + kc] = vl;
  }
  __syncthreads();

  f32x4 acc[4][4];
  #pragma unroll
  for (int i=0;i<4;++i)
    #pragma unroll
    for (int j=0;j<4;++j) acc[i][j] = (f32x4)(0.0f);

  #pragma unroll
  for (int k0 = 0; k0 < KIN; k0 += 32){
    bf16x8 ah[4], al[4], bh[4], bl[4];
    #pragma unroll
    for (int fa=0; fa<4; ++fa){
      ah[fa] = *(const bf16x8*)&Ah[(wr + fa*16 + l15)*SA + k0 + 8*lg];
      al[fa] = *(const bf16x8*)&Al[(wr + fa*16 + l15)*SA + k0 + 8*lg];
    }
    #pragma unroll
    for (int fb=0; fb<4; ++fb){
      bh[fb] = *(const bf16x8*)&W1h[(wc0 + fb*16 + l15)*KIN + k0 + 8*lg];
      bl[fb] = *(const bf16x8*)&W1l[(wc0 + fb*16 + l15)*KIN + k0 + 8*lg];
    }
    #pragma unroll
    for (int fa=0; fa<4; ++fa)
      #pragma unroll
      for (int fb=0; fb<4; ++fb){
        acc[fa][fb] = __builtin_amdgcn_mfma_f32_16x16x32_bf16(ah[fa], bh[fb], acc[fa][fb], 0, 0, 0);
        acc[fa][fb] = __builtin_amdgcn_mfma_f32_16x16x32_bf16(al[fa], bh[fb], acc[fa][fb], 0, 0, 0);
        acc[fa][fb] = __builtin_amdgcn_mfma_f32_16x16x32_bf16(ah[fa], bl[fb], acc[fa][fb], 0, 0, 0);
      }
  }
  __syncthreads();

  {
    float b1v[4];
    #pragma unroll
    for (int fb=0; fb<4; ++fb) b1v[fb] = b1[wc0 + fb*16 + l15];
    #pragma unroll
    for (int fa=0; fa<4; ++fa)
      #pragma unroll
      for (int fb=0; fb<4; ++fb)
        #pragma unroll
        for (int r=0; r<4; ++r){
          float v = fmaxf(acc[fa][fb][r] + b1v[fb], 0.0f);
          unsigned short h = f2bf(v);
          int idx = (wr + fa*16 + lg*4 + r)*136 + (wc0 + fb*16 + l15);
          Ah[idx] = h;
          Al[idx] = f2bf(v - bf2f(h));
        }
  }
  __syncthreads();

  f32x4 acc2[4][4];
  #pragma unroll
  for (int i=0;i<4;++i)
    #pragma unroll
    for (int j=0;j<4;++j) acc2[i][j] = (f32x4)(0.0f);

  #pragma unroll
  for (int k0 = 0; k0 < 128; k0 += 32){
    bf16x8 ah[4], al[4], bh[4], bl[4];
    #pragma unroll
    for (int fa=0; fa<4; ++fa){
      ah[fa] = *(const bf16x8*)&Ah[(wr + fa*16 + l15)*136 + k0 + 8*lg];
      al[fa] = *(const bf16x8*)&Al[(wr + fa*16 + l15)*136 + k0 + 8*lg];
    }
    #pragma unroll
    for (int fb=0; fb<4; ++fb){
      bh[fb] = *(const bf16x8*)&W2h[(wc0 + fb*16 + l15)*128 + k0 + 8*lg];
      bl[fb] = *(const bf16x8*)&W2l[(wc0 + fb*16 + l15)*128 + k0 + 8*lg];
    }
    #pragma unroll
    for (int fa=0; fa<4; ++fa)
      #pragma unroll
      for (int fb=0; fb<4; ++fb){
        acc2[fa][fb] = __builtin_amdgcn_mfma_f32_16x16x32_bf16(ah[fa], bh[fb], acc2[fa][fb], 0, 0, 0);
        acc2[fa][fb] = __builtin_amdgcn_mfma_f32_16x16x32_bf16(al[fa], bh[fb], acc2[fa][fb], 0, 0, 0);
        acc2[fa][fb] = __builtin_amdgcn_mfma_f32_16x16x32_bf16(ah[fa], bl[fb], acc2[fa][fb], 0, 0, 0);
      }
  }

  float b2v[4]; int cc[4];
  #pragma unroll
  for (int fb=0; fb<4; ++fb){ cc[fb] = wc0 + fb*16 + l15; b2v[fb] = b2[cc[fb]]; }
  float ps[4] = {0,0,0,0}, pq[4] = {0,0,0,0};
  #pragma unroll
  for (int fa=0; fa<4; ++fa)
    #pragma unroll
    for (int fb=0; fb<4; ++fb)
      #pragma unroll
      for (int r=0; r<4; ++r){
        int row = row0 + wr + fa*16 + lg*4 + r;
        float v = fmaxf(acc2[fa][fb][r] + b2v[fb], 0.0f);
        if (row < NN){
          Y[(size_t)row*128 + cc[fb]] = v;
          ps[fb] += v; pq[fb] += v*v;
        }
      }
  #pragma unroll
  for (int fb=0; fb<4; ++fb){
    float s = ps[fb]; s += __shfl_xor(s, 16); s += __shfl_xor(s, 32);
    float q = pq[fb]; q += __shfl_xor(q, 16); q += __shfl_xor(q, 32);
    if (lane < 16){ atomicAdd(&stats[cc[fb]], s); atomicAdd(&stats[128 + cc[fb]], q); }
  }
}

// ======================= BN helpers =======================
__global__ void bn_finalize_k(const float* __restrict__ stats, const float* __restrict__ gamma,
                              const float* __restrict__ beta, float* __restrict__ sshift, int C, float invN){
  int c = blockIdx.x*blockDim.x + threadIdx.x; if (c >= C) return;
  float mean = stats[c]*invN;
  float var  = fmaxf(stats[C+c]*invN - mean*mean, 0.0f);
  float inv  = rsqrtf(var + 1e-5f);
  float sc   = gamma[c]*inv;
  sshift[c] = sc; sshift[C+c] = beta[c] - mean*sc;
}

// fused BN apply + per-graph pooling: one wave per graph
__global__ __launch_bounds__(256) void bn_pool_k(const float* __restrict__ Y,
    const float* __restrict__ sshift, const int* __restrict__ gstart,
    float* __restrict__ Hb, float* __restrict__ pool, int layer)
{
  int g = blockIdx.x*4 + (threadIdx.x >> 6);
  if (g >= NB) return;
  int lane = threadIdx.x & 63;
  int c0 = lane << 1;
  float sc0 = sshift[c0],     sc1 = sshift[c0+1];
  float sh0 = sshift[128+c0], sh1 = sshift[128+c0+1];
  int n0 = gstart[g], n1 = gstart[g+1];
  const float2* Yp = (const float2*)Y;
  float2* Hp = (float2*)Hb;
  float2 acc = make_float2(0.f, 0.f);
  for (int r = n0; r < n1; ++r){
    float2 y = Yp[(size_t)r*64 + lane];
    float2 h = make_float2(y.x*sc0 + sh0, y.y*sc1 + sh1);
    Hp[(size_t)r*64 + lane] = h;
    acc.x += h.x; acc.y += h.y;
  }
  ((float2*)pool)[(size_t)g*320 + layer*64 + lane] = acc;
}

// ======================= LSTM =======================
// e2 layout: [t][b][64]
__global__ __launch_bounds__(256) void embed_k(const int* __restrict__ smi,
    const unsigned short* __restrict__ emb_bf, unsigned short* __restrict__ e2){
  int gid = blockIdx.x*256 + threadIdx.x;
  int tb = gid >> 4;
  if (tb >= TT*BPAD) return;
  int t = tb / BPAD, b = tb - t*BPAD;
  int k4 = (gid & 15) << 2;
  uint2 v = make_uint2(0u, 0u);
  if (b < NB){
    int tok = smi[b*TT + t];
    v = *(const uint2*)&emb_bf[tok*64 + k4];
  }
  *(uint2*)&e2[(size_t)tb*64 + k4] = v;
}

// One LSTM step: gates = [h|e_t] @ Wc2^T + bias; double-buffered LDS, 1 barrier/K-step.
// Block = 128 rows x 128 gate-cols (cols permuted [hc][gate][j15]); wave = 64 rows x (4 gates x 16 j).
// 1D grid of 480 with XCD-aware swizzle: XCD x owns row-tiles {3x..3x+2} x all 20 j-tiles,
// so Wc2 (3.6 MB) + A-slice (528 KB) stay in the XCD's private L2 across j-tiles.
__global__ __launch_bounds__(256) void lstm_step_k(const unsigned short* __restrict__ hprev,
    unsigned short* __restrict__ hnext, float* __restrict__ cbuf,
    const unsigned short* __restrict__ e2, const unsigned short* __restrict__ Wc2,
    const float* __restrict__ biasc, int t, float* __restrict__ hfin)
{
  __shared__ __align__(16) unsigned short As[2][128*40];
  __shared__ __align__(16) unsigned short Bs[2][128*40];
  const int tid = threadIdx.x, lane = tid & 63, w = tid >> 6;
  // XCD swizzle: 480 blocks = 8 XCDs x 60; per XCD: rt = xcd*3 + i%3, jt = i/3
  const int bid = blockIdx.x;
  const int xcd = bid & 7, idx = bid >> 3;
  const int rt = xcd*3 + (idx % 3);
  const int jt = idx / 3;                    // j-tile of 32
  const int row0 = rt * 128;
  const int l15 = lane & 15, lg = lane >> 4;
  const int wr = (w >> 1)*64, wc0 = (w & 1)*64;

  const int srow = tid >> 2, skc = (tid & 3) << 3;
  const unsigned short* A0 = hprev + (size_t)(row0 + srow)*HID;
  const unsigned short* A1 = hprev + (size_t)(row0 + srow + 64)*HID;
  const unsigned short* E0 = e2 + ((size_t)t*BPAD + row0 + srow)*64;
  const unsigned short* E1 = e2 + ((size_t)t*BPAD + row0 + srow + 64)*64;
  const unsigned short* B0 = Wc2 + (size_t)(jt*128 + srow)*704;
  const unsigned short* B1 = Wc2 + (size_t)(jt*128 + srow + 64)*704;

  // prologue: stage k=0 (always h-part)
  *(ushort8*)&As[0][srow*40 + skc]      = *(const ushort8*)&A0[skc];
  *(ushort8*)&As[0][(srow+64)*40 + skc] = *(const ushort8*)&A1[skc];
  *(ushort8*)&Bs[0][srow*40 + skc]      = *(const ushort8*)&B0[skc];
  *(ushort8*)&Bs[0][(srow+64)*40 + skc] = *(const ushort8*)&B1[skc];
  __syncthreads();

  f32x4 acc[4][4];
  #pragma unroll
  for (int i=0;i<4;++i)
    #pragma unroll
    for (int j=0;j<4;++j) acc[i][j] = (f32x4)(0.0f);

  int p = 0;
  for (int kk = 0; kk < 22; ++kk){
    ushort8 va0, va1, vb0, vb1;
    const int k1 = (kk+1)*32;
    if (kk < 21){
      if (k1 < 640){
        va0 = *(const ushort8*)&A0[k1 + skc];
        va1 = *(const ushort8*)&A1[k1 + skc];
      } else {
        va0 = *(const ushort8*)&E0[k1 - 640 + skc];
        va1 = *(const ushort8*)&E1[k1 - 640 + skc];
      }
      vb0 = *(const ushort8*)&B0[k1 + skc];
      vb1 = *(const ushort8*)&B1[k1 + skc];
    }
    bf16x8 a[4], b[4];
    #pragma unroll
    for (int fa=0; fa<4; ++fa) a[fa] = *(const bf16x8*)&As[p][(wr + fa*16 + l15)*40 + 8*lg];
    #pragma unroll
    for (int fb=0; fb<4; ++fb) b[fb] = *(const bf16x8*)&Bs[p][(wc0 + fb*16 + l15)*40 + 8*lg];
    __builtin_amdgcn_s_setprio(1);
    #pragma unroll
    for (int fa=0; fa<4; ++fa)
      #pragma unroll
      for (int fb=0; fb<4; ++fb)
        acc[fa][fb] = __builtin_amdgcn_mfma_f32_16x16x32_bf16(a[fa], b[fb], acc[fa][fb], 0, 0, 0);
    __builtin_amdgcn_s_setprio(0);
    if (kk < 21){
      *(ushort8*)&As[p^1][srow*40 + skc]      = va0;
      *(ushort8*)&As[p^1][(srow+64)*40 + skc] = va1;
      *(ushort8*)&Bs[p^1][srow*40 + skc]      = vb0;
      *(ushort8*)&Bs[p^1][(srow+64)*40 + skc] = vb1;
    }
    __syncthreads();
    p ^= 1;
  }

  // epilogue: fragment fb == gate; j = jt*32 + (w&1)*16 + l15
  const int j = jt*32 + (w & 1)*16 + l15;
  float bi = biasc[j], bf_ = biasc[640+j], bg = biasc[1280+j], bo = biasc[1920+j];
  #pragma unroll
  for (int fa=0; fa<4; ++fa){
    #pragma unroll
    for (int r=0; r<4; ++r){
      int br = row0 + wr + fa*16 + lg*4 + r;
      float iv = acc[fa][0][r] + bi;
      float fv = acc[fa][1][r] + bf_;
      float gv = acc[fa][2][r] + bg;
      float ov = acc[fa][3][r] + bo;
      size_t idx2 = (size_t)br*HID + j;
      float co = cbuf[idx2];
      float cn = sigf(fv)*co + sigf(iv)*tanhf_fast(gv);
      cbuf[idx2] = cn;
      float hv = sigf(ov)*tanhf_fast(cn);
      hnext[idx2] = f2bf(hv);
      if (hfin) hfin[idx2] = hv;
    }
  }
}

// ======================= split-precision GEMM (heads) =======================
template<int DO_STATS>
__global__ __launch_bounds__(256) void gemm_split_k(const float* __restrict__ A,
    const unsigned short* __restrict__ Bh, const unsigned short* __restrict__ Bl,
    const float* __restrict__ bias, float* __restrict__ outp, float* __restrict__ stats,
    int Mvalid, int Nc, int K)
{
  __shared__ __align__(16) unsigned short Ah[128*40];
  __shared__ __align__(16) unsigned short Al[128*40];
  const int tid = threadIdx.x, lane = tid & 63, w = tid >> 6;
  const int row0 = blockIdx.x * 128, col0 = blockIdx.y * 128;
  const int wr = (w >> 1)*64, wc0 = (w & 1)*64;
  const int l15 = lane & 15, lg = lane >> 4;

  f32x4 acc[4][4];
  #pragma unroll
  for (int i=0;i<4;++i)
    #pragma unroll
    for (int j=0;j<4;++j) acc[i][j] = (f32x4)(0.0f);

  for (int k0 = 0; k0 < K; k0 += 32){
    #pragma unroll
    for (int i=0;i<2;++i){
      int chunk = tid + 256*i;
      int row = chunk >> 2, kc = (chunk & 3) << 3;
      const float* sp = A + (size_t)(row0+row)*K + k0 + kc;
      float4 a0 = *(const float4*)sp;
      float4 a1 = *(const float4*)(sp + 4);
      float vv[8] = {a0.x,a0.y,a0.z,a0.w,a1.x,a1.y,a1.z,a1.w};
      ushort8 vh, vl;
      #pragma unroll
      for (int q=0;q<8;++q){ unsigned short h = f2bf(vv[q]); vh[q]=h; vl[q]=f2bf(vv[q]-bf2f(h)); }
      *(ushort8*)&Ah[row*40 + kc] = vh;
      *(ushort8*)&Al[row*40 + kc] = vl;
    }
    __syncthreads();
    bf16x8 ah[4], al[4], bh[4], bl[4];
    #pragma unroll
    for (int fa=0; fa<4; ++fa){
      ah[fa] = *(const bf16x8*)&Ah[(wr + fa*16 + l15)*40 + 8*lg];
      al[fa] = *(const bf16x8*)&Al[(wr + fa*16 + l15)*40 + 8*lg];
    }
    #pragma unroll
    for (int fb=0; fb<4; ++fb){
      bh[fb] = *(const bf16x8*)&Bh[(size_t)(col0 + wc0 + fb*16 + l15)*K + k0 + 8*lg];
      bl[fb] = *(const bf16x8*)&Bl[(size_t)(col0 + wc0 + fb*16 + l15)*K + k0 + 8*lg];
    }
    #pragma unroll
    for (int fa=0; fa<4; ++fa)
      #pragma unroll
      for (int fb=0; fb<4; ++fb){
        acc[fa][fb] = __builtin_amdgcn_mfma_f32_16x16x32_bf16(ah[fa], bh[fb], acc[fa][fb], 0, 0, 0);
        acc[fa][fb] = __builtin_amdgcn_mfma_f32_16x16x32_bf16(al[fa], bh[fb], acc[fa][fb], 0, 0, 0);
        acc[fa][fb] = __builtin_amdgcn_mfma_f32_16x16x32_bf16(ah[fa], bl[fb], acc[fa][fb], 0, 0, 0);
      }
    __syncthreads();
  }

  float bv[4]; int cc[4];
  #pragma unroll
  for (int fb=0; fb<4; ++fb){ cc[fb] = col0 + wc0 + fb*16 + l15; bv[fb] = bias ? bias[cc[fb]] : 0.0f; }
  float ps[4] = {0,0,0,0}, pq[4] = {0,0,0,0};
  #pragma unroll
  for (int fa=0; fa<4; ++fa)
    #pragma unroll
    for (int fb=0; fb<4; ++fb)
      #pragma unroll
      for (int r=0; r<4; ++r){
        int row = row0 + wr + fa*16 + lg*4 + r;
        float v = acc[fa][fb][r] + bv[fb];
        if (row < Mvalid){
          outp[(size_t)row*Nc + cc[fb]] = v;
          if (DO_STATS){ ps[fb] += v; pq[fb] += v*v; }
        }
      }
  if (DO_STATS){
    #pragma unroll
    for (int fb=0; fb<4; ++fb){
      float s = ps[fb]; s += __shfl_xor(s, 16); s += __shfl_xor(s, 32);
      float q = pq[fb]; q += __shfl_xor(q, 16); q += __shfl_xor(q, 32);
      if (lane < 16){ atomicAdd(&stats[cc[fb]], s); atomicAdd(&stats[Nc + cc[fb]], q); }
    }
  }
}

__global__ __launch_bounds__(256) void bn_apply_head_k(const float* __restrict__ Zpre,
    const float* __restrict__ sshift, float* __restrict__ z1f){
  int gid = blockIdx.x*256 + threadIdx.x;
  int r = gid >> 7;
  if (r >= BPAD) return;
  int c0 = (gid & 127) << 2;
  float4 o = make_float4(0.f,0.f,0.f,0.f);
  if (r < NB){
    float4 v = *(const float4*)&Zpre[(size_t)r*512 + c0];
    o.x = fmaxf(v.x*sshift[c0+0] + sshift[512+c0+0], 0.0f);
    o.y = fmaxf(v.y*sshift[c0+1] + sshift[512+c0+1], 0.0f);
    o.z = fmaxf(v.z*sshift[c0+2] + sshift[512+c0+2], 0.0f);
    o.w = fmaxf(v.w*sshift[c0+3] + sshift[512+c0+3], 0.0f);
  }
  *(float4*)&z1f[(size_t)r*512 + c0] = o;
}

__global__ __launch_bounds__(256) void rownorm_k(const float* __restrict__ in, float* __restrict__ outp){
  int r = blockIdx.x;
  const float* p = in + (size_t)r*768;
  float ss = 0.0f;
  #pragma unroll
  for (int i = 0; i < 3; ++i){ float v = p[threadIdx.x + 256*i]; ss += v*v; }
  #pragma unroll
  for (int m = 1; m < 64; m <<= 1) ss += __shfl_xor(ss, m);
  __shared__ float red[4];
  if ((threadIdx.x & 63) == 0) red[threadIdx.x >> 6] = ss;
  __syncthreads();
  float tot = red[0] + red[1] + red[2] + red[3];
  float inv = 1.0f / fmaxf(sqrtf(tot), 1e-12f);
  float* q = outp + (size_t)r*768;
  #pragma unroll
  for (int i = 0; i < 3; ++i) q[threadIdx.x + 256*i] = p[threadIdx.x + 256*i]*inv;
}

// ======================= launcher =======================
static inline int cdiv(long a, long b){ return (int)((a + b - 1)/b); }

extern "C" void kernel_launch(void* const* d_in, const int* in_sizes, int n_in,
                              void* d_out, int out_size, void* d_ws, size_t ws_size,
                              hipStream_t stream)
{
  const float* x        = (const float*)d_in[0];
  const int*   edges    = (const int*)d_in[1];
  const int*   batch    = (const int*)d_in[2];
  const int*   smi      = (const int*)d_in[3];
  const float* gin0_w1  = (const float*)d_in[4];
  const float* gin0_b1  = (const float*)d_in[5];
  const float* gin0_w2  = (const float*)d_in[6];
  const float* gin0_b2  = (const float*)d_in[7];
  const float* ginr_w1  = (const float*)d_in[8];
  const float* ginr_b1  = (const float*)d_in[9];
  const float* ginr_w2  = (const float*)d_in[10];
  const float* ginr_b2  = (const float*)d_in[11];
  const float* bn_gamma = (const float*)d_in[12];
  const float* bn_beta  = (const float*)d_in[13];
  const float* emb      = (const float*)d_in[14];
  const float* w_ih     = (const float*)d_in[15];
  const float* w_hh     = (const float*)d_in[16];
  const float* b_ih     = (const float*)d_in[17];
  const float* b_hh     = (const float*)d_in[18];
  const float* g_w1     = (const float*)d_in[19];
  const float* g_b1     = (const float*)d_in[20];
  const float* g_bng    = (const float*)d_in[21];
  const float* g_bnb    = (const float*)d_in[22];
  const float* g_w2     = (const float*)d_in[23];
  float* outp = (float*)d_out;
  const int* srcs = edges;
  const int* dsts = edges + NE;

  char* base = (char*)d_ws;
  size_t off = 0;
  auto carve = [&](size_t bytes)->char*{ char* p = base + off; off += (bytes + 255) & ~(size_t)255; return p; };
  float* z_gin = (float*)carve((size_t)NPAD*128*4);      // reused for head temps
  float* y_gin = (float*)carve((size_t)NPAD*128*4);      // reused for e2
  float* h_gin = (float*)carve((size_t)NPAD*128*4);      // reused for LSTM state
  float* pool  = (float*)carve((size_t)BPAD*HID*4);
  unsigned short* Wc2    = (unsigned short*)carve((size_t)2560*704*2);
  float*          biasc  = (float*)carve(2560*4);
  unsigned short* emb_bf = (unsigned short*)carve(4096*2);
  unsigned short* w1t0h  = (unsigned short*)carve(128*32*2);
  unsigned short* w1t0l  = (unsigned short*)carve(128*32*2);
  unsigned short* w2t0h  = (unsigned short*)carve(128*128*2);
  unsigned short* w2t0l  = (unsigned short*)carve(128*128*2);
  unsigned short* w1trh  = (unsigned short*)carve(4*16384*2);
  unsigned short* w1trl  = (unsigned short*)carve(4*16384*2);
  unsigned short* w2trh  = (unsigned short*)carve(4*16384*2);
  unsigned short* w2trl  = (unsigned short*)carve(4*16384*2);
  unsigned short* gw1th  = (unsigned short*)carve(512*640*2);
  unsigned short* gw1tl  = (unsigned short*)carve(512*640*2);
  unsigned short* gw2th  = (unsigned short*)carve(768*512*2);
  unsigned short* gw2tl  = (unsigned short*)carve(768*512*2);
  float* stats  = (float*)carve(1024*4);
  float* sshift = (float*)carve(1024*4);
  int* deg    = (int*)carve((size_t)NN*4);
  int* cursor = (int*)carve((size_t)NN*4);
  int* rowptr = (int*)carve((size_t)(NN+1)*4);
  int* bsum   = (int*)carve(512);
  int* eidx   = (int*)carve((size_t)NE*4);
  int* gstart = (int*)carve((size_t)(NB+1)*4);

  // aliases (regions free at the time of reuse)
  unsigned short* e2     = (unsigned short*)y_gin;                       // [t][b][64], 50.3 MB
  unsigned short* h_a    = (unsigned short*)h_gin;
  unsigned short* h_b    = h_a + (size_t)BPAD*HID;
  float*          c_buf  = (float*)(h_b + (size_t)BPAD*HID);
  float*          hfin   = c_buf + (size_t)BPAD*HID;                     // fp32 final h
  float*          z1pre  = (float*)z_gin;
  float*          z1f    = z1pre + (size_t)BPAD*512;
  float*          outtmp = z1f + (size_t)BPAD*512;

  // ---- prep (weight conversions) ----
  wc2_build_k<<<cdiv((long)2560*704,256),256,0,stream>>>(w_hh, w_ih, Wc2);
  add_k<<<cdiv(2560,256),256,0,stream>>>(b_ih, b_hh, biasc, 2560);
  cvt_k<<<cdiv(4096,256),256,0,stream>>>(emb, emb_bf, 4096);
  transpose_cvt_split_k<<<cdiv(32*128,256),256,0,stream>>>(gin0_w1, w1t0h, w1t0l, 32, 128);
  transpose_cvt_split_k<<<cdiv(16384,256),256,0,stream>>>(gin0_w2, w2t0h, w2t0l, 128, 128);
  for (int i = 0; i < 4; ++i){
    transpose_cvt_split_k<<<cdiv(16384,256),256,0,stream>>>(ginr_w1 + (size_t)i*16384, w1trh + (size_t)i*16384, w1trl + (size_t)i*16384, 128, 128);
    transpose_cvt_split_k<<<cdiv(16384,256),256,0,stream>>>(ginr_w2 + (size_t)i*16384, w2trh + (size_t)i*16384, w2trl + (size_t)i*16384, 128, 128);
  }
  transpose_cvt_split_k<<<cdiv(640*512,256),256,0,stream>>>(g_w1, gw1th, gw1tl, 640, 512);
  transpose_cvt_split_k<<<cdiv(512*768,256),256,0,stream>>>(g_w2, gw2th, gw2tl, 512, 768);

  // ---- CSR + graph bounds (once) ----
  hipMemsetAsync(deg, 0, (size_t)NN*4, stream);
  deg_hist_k<<<cdiv(NE,256),256,0,stream>>>(dsts, deg);
  scan_bsum_k<<<NBLK,256,0,stream>>>(deg, bsum);
  scan_off_k<<<1,64,0,stream>>>(bsum);
  scan_write_k<<<NBLK,256,0,stream>>>(deg, bsum, rowptr, cursor);
  csr_fill_k<<<cdiv(NE,256),256,0,stream>>>(srcs, dsts, cursor, eidx);
  gbound_k<<<cdiv(NN,256),256,0,stream>>>(batch, gstart);

  // ---- GIN encoder ----
  for (int l = 0; l < 5; ++l){
    hipMemsetAsync(stats, 0, 1024*4, stream);
    if (l == 0)
      agg32_k<<<cdiv((long)NN*32,256),256,0,stream>>>(rowptr, eidx, x, z_gin);
    else
      agg128_k<<<cdiv((long)NN*64,256),256,0,stream>>>(rowptr, eidx, h_gin, z_gin);
    if (l == 0)
      gin_mlp_k<32><<<NPAD/128,256,0,stream>>>(z_gin, w1t0h, w1t0l, w2t0h, w2t0l, gin0_b1, gin0_b2, y_gin, stats);
    else
      gin_mlp_k<128><<<NPAD/128,256,0,stream>>>(z_gin, w1trh + (size_t)(l-1)*16384, w1trl + (size_t)(l-1)*16384,
                                                w2trh + (size_t)(l-1)*16384, w2trl + (size_t)(l-1)*16384,
                                                ginr_b1 + (l-1)*128, ginr_b2 + (l-1)*128, y_gin, stats);
    bn_finalize_k<<<1,128,0,stream>>>(stats, bn_gamma + l*128, bn_beta + l*128, sshift, 128, 1.0f/NN);
    bn_pool_k<<<cdiv(NB,4),256,0,stream>>>(y_gin, sshift, gstart, h_gin, pool, l);
  }

  // ---- LSTM (per-step launches; XCD-swizzled 1D grid of 480) ----
  embed_k<<<cdiv((long)TT*BPAD*16,256),256,0,stream>>>(smi, emb_bf, e2);
  hipMemsetAsync(h_a, 0, (size_t)BPAD*HID*2, stream);
  hipMemsetAsync(c_buf, 0, (size_t)BPAD*HID*4, stream);
  for (int t = 0; t < TT; ++t){
    const unsigned short* hin = (t & 1) ? h_b : h_a;
    unsigned short* hout      = (t & 1) ? h_a : h_b;
    lstm_step_k<<<480,256,0,stream>>>(hin, hout, c_buf, e2, Wc2, biasc, t,
                                      (t == TT-1) ? hfin : nullptr);
  }

  // ---- heads ----
  const float* headAf[2] = { pool, hfin };
  for (int hd = 0; hd < 2; ++hd){
    hipMemsetAsync(stats, 0, 1024*4, stream);
    gemm_split_k<1><<<dim3(BPAD/128, 4),256,0,stream>>>(headAf[hd], gw1th, gw1tl, g_b1, z1pre, stats, NB, 512, 640);
    bn_finalize_k<<<2,256,0,stream>>>(stats, g_bng, g_bnb, sshift, 512, 1.0f/NB);
    bn_apply_head_k<<<cdiv((long)BPAD*128,256),256,0,stream>>>(z1pre, sshift, z1f);
    gemm_split_k<0><<<dim3(BPAD/128, 6),256,0,stream>>>(z1f, gw2th, gw2tl, nullptr, outtmp, nullptr, NB, 768, 512);
    rownorm_k<<<NB,256,0,stream>>>(outtmp, outp + (size_t)hd*NB*768);
  }
}

// Round 11
// 4278.951 us; speedup vs baseline: 1.2123x; 1.0246x over previous
//
#include <hip/hip_runtime.h>

typedef __bf16 bf16x8 __attribute__((ext_vector_type(8)));
typedef float f32x4 __attribute__((ext_vector_type(4)));
typedef unsigned short ushort8 __attribute__((ext_vector_type(8)));

#define DEV static __device__ __forceinline__

DEV unsigned short f2bf(float f){
  unsigned int u = __builtin_bit_cast(unsigned int, f);
  u += 0x7fffu + ((u >> 16) & 1u);   // RNE; inputs finite
  return (unsigned short)(u >> 16);
}
DEV float bf2f(unsigned short u){
  return __builtin_bit_cast(float, ((unsigned int)u) << 16);
}
DEV float bfu_lo(unsigned int v){ return __builtin_bit_cast(float, v << 16); }
DEV float bfu_hi(unsigned int v){ return __builtin_bit_cast(float, v & 0xFFFF0000u); }
DEV float sigf(float x){ return 1.0f/(1.0f + __expf(-x)); }
DEV float tanhf_fast(float x){
  float ax = fabsf(x);
  float e = __expf(2.0f*ax);
  float r = 1.0f - 2.0f/(e + 1.0f);
  return copysignf(r, x);
}

static constexpr int NN   = 100000;   // nodes
static constexpr int NPAD = 100096;   // 782*128
static constexpr int NE   = 1600000;  // edges
static constexpr int NB   = 3000;     // graphs / batch
static constexpr int BPAD = 3072;     // padded batch (24*128)
static constexpr int TT   = 128;      // seq len
static constexpr int HID  = 640;      // LSTM hidden
static constexpr int SCAN_B = 1024;
static constexpr int NBLK = (NN + SCAN_B - 1)/SCAN_B;   // 98

// ======================= prep kernels =======================
__global__ void cvt_k(const float* __restrict__ s, unsigned short* __restrict__ d, int n){
  int i = blockIdx.x*256 + threadIdx.x; if (i < n) d[i] = f2bf(s[i]);
}
__global__ void transpose_cvt_split_k(const float* __restrict__ s, unsigned short* __restrict__ dh,
                                      unsigned short* __restrict__ dl, int R, int C){
  int i = blockIdx.x*256 + threadIdx.x; if (i >= R*C) return;
  int r = i / C, c = i - r*C;
  float v = s[i];
  unsigned short hi = f2bf(v);
  dh[c*R + r] = hi;
  dl[c*R + r] = f2bf(v - bf2f(hi));
}
// Wc2 row n2 = jt*128 + hc*64 + gate*16 + j15  <->  gate-row n = gate*640 + jt*32 + hc*16 + j15
__global__ void wc2_build_k(const float* __restrict__ whh, const float* __restrict__ wih,
                            unsigned short* __restrict__ wc2){
  int i = blockIdx.x*256 + threadIdx.x; if (i >= 2560*704) return;
  int n2 = i / 704, k = i - n2*704;
  int jt = n2 >> 7, rem = n2 & 127;
  int hc = rem >> 6, gate = (rem >> 4) & 3, j15 = rem & 15;
  int n = gate*640 + jt*32 + hc*16 + j15;
  float v = (k < 640) ? whh[n*640 + k] : wih[n*64 + (k - 640)];
  wc2[i] = f2bf(v);
}
__global__ void add_k(const float* __restrict__ a, const float* __restrict__ b, float* __restrict__ o, int n){
  int i = blockIdx.x*256 + threadIdx.x; if (i < n) o[i] = a[i] + b[i];
}

// ======================= CSR build =======================
__global__ __launch_bounds__(256) void deg_hist_k(const int* __restrict__ dsts, int* __restrict__ deg){
  int e = blockIdx.x*256 + threadIdx.x; if (e < NE) atomicAdd(&deg[dsts[e]], 1);
}
__global__ __launch_bounds__(256) void scan_bsum_k(const int* __restrict__ deg, int* __restrict__ bsum){
  __shared__ int red[4];
  int b = blockIdx.x, tid = threadIdx.x;
  int base = b*SCAN_B + tid*4;
  int s = 0;
  #pragma unroll
  for (int q = 0; q < 4; ++q){ int idx = base + q; s += (idx < NN) ? deg[idx] : 0; }
  #pragma unroll
  for (int m = 1; m < 64; m <<= 1) s += __shfl_xor(s, m);
  if ((tid & 63) == 0) red[tid >> 6] = s;
  __syncthreads();
  if (tid == 0) bsum[b] = red[0] + red[1] + red[2] + red[3];
}
__global__ void scan_off_k(int* __restrict__ bsum){
  if (threadIdx.x == 0){
    int run = 0;
    for (int i = 0; i < NBLK; ++i){ int t = bsum[i]; bsum[i] = run; run += t; }
  }
}
__global__ __launch_bounds__(256) void scan_write_k(const int* __restrict__ deg, const int* __restrict__ bsum,
                                                    int* __restrict__ rowptr, int* __restrict__ cursor){
  __shared__ int tsum[256];
  int b = blockIdx.x, tid = threadIdx.x;
  int base = b*SCAN_B + tid*4;
  int v[4]; int s = 0;
  #pragma unroll
  for (int q = 0; q < 4; ++q){ int idx = base + q; v[q] = (idx < NN) ? deg[idx] : 0; s += v[q]; }
  tsum[tid] = s;
  __syncthreads();
  for (int offt = 1; offt < 256; offt <<= 1){
    int y = (tid >= offt) ? tsum[tid - offt] : 0;
    __syncthreads();
    tsum[tid] += y;
    __syncthreads();
  }
  int run = bsum[b] + tsum[tid] - s;
  #pragma unroll
  for (int q = 0; q < 4; ++q){
    int idx = base + q;
    if (idx < NN){ rowptr[idx] = run; cursor[idx] = run; }
    run += v[q];
  }
  if (b == 0 && tid == 0) rowptr[NN] = NE;
}
__global__ __launch_bounds__(256) void csr_fill_k(const int* __restrict__ srcs, const int* __restrict__ dsts,
                                                  int* __restrict__ cursor, int* __restrict__ eidx){
  int e = blockIdx.x*256 + threadIdx.x; if (e >= NE) return;
  int d = dsts[e];
  int pos = atomicAdd(&cursor[d], 1);
  eidx[pos] = srcs[e];
}

__global__ __launch_bounds__(256) void gbound_k(const int* __restrict__ batch, int* __restrict__ gstart){
  int i = blockIdx.x*256 + threadIdx.x;
  if (i >= NN) return;
  int bi = batch[i];
  int bp = (i == 0) ? -1 : batch[i-1];
  for (int g = bp + 1; g <= bi; ++g) gstart[g] = i;
  if (i == NN-1){
    for (int g = bi + 1; g <= NB; ++g) gstart[g] = NN;
  }
}

// ======================= GIN: gather aggregation =======================
// bf16 gather: H stored as packed 2xbf16 per uint ([NN][64] uints = cols 2l,2l+1).
// One wave per row; fp32 accumulation; z written fp32.
__global__ __launch_bounds__(256) void agg128_k(const int* __restrict__ rowptr, const int* __restrict__ eidx,
    const unsigned int* __restrict__ Hbf, float* __restrict__ Z){
  int wid = (blockIdx.x*256 + threadIdx.x) >> 6;
  if (wid >= NN) return;
  int lane = threadIdx.x & 63;
  int n0 = rowptr[wid], n1 = rowptr[wid+1];
  unsigned int v = Hbf[(size_t)wid*64 + lane];
  float ax = bfu_lo(v), ay = bfu_hi(v);
  int i = n0;
  for (; i + 1 < n1; i += 2){
    int s0 = eidx[i], s1 = eidx[i+1];
    unsigned int v0 = Hbf[(size_t)s0*64 + lane];
    unsigned int v1 = Hbf[(size_t)s1*64 + lane];
    ax += bfu_lo(v0) + bfu_lo(v1);
    ay += bfu_hi(v0) + bfu_hi(v1);
  }
  if (i < n1){
    unsigned int v0 = Hbf[(size_t)eidx[i]*64 + lane];
    ax += bfu_lo(v0); ay += bfu_hi(v0);
  }
  ((float2*)Z)[(size_t)wid*64 + lane] = make_float2(ax, ay);
}
__global__ __launch_bounds__(256) void agg32_k(const int* __restrict__ rowptr, const int* __restrict__ eidx,
    const float* __restrict__ X, float* __restrict__ Z){
  int r = (blockIdx.x*256 + threadIdx.x) >> 5;
  if (r >= NN) return;
  int l = threadIdx.x & 31;
  int n0 = rowptr[r], n1 = rowptr[r+1];
  float acc = X[(size_t)r*32 + l];
  int i = n0;
  for (; i + 1 < n1; i += 2){
    int s0 = eidx[i], s1 = eidx[i+1];
    acc += X[(size_t)s0*32 + l] + X[(size_t)s1*32 + l];
  }
  if (i < n1) acc += X[(size_t)eidx[i]*32 + l];
  Z[(size_t)r*32 + l] = acc;
}

// ======================= GIN: fused 2-layer MLP (split-precision bf16 MFMA) =======================
template<int KIN>
__global__ __launch_bounds__(256) void gin_mlp_k(const float* __restrict__ Z,
    const unsigned short* __restrict__ W1h, const unsigned short* __restrict__ W1l,
    const unsigned short* __restrict__ W2h, const unsigned short* __restrict__ W2l,
    const float* __restrict__ b1, const float* __restrict__ b2,
    float* __restrict__ Y, float* __restrict__ stats)
{
  constexpr int SA = KIN + 8;
  __shared__ __align__(16) unsigned short Ah[128*136];
  __shared__ __align__(16) unsigned short Al[128*136];
  const int tid = threadIdx.x, lane = tid & 63, w = tid >> 6;
  const int row0 = blockIdx.x * 128;
  const int wr = (w >> 1)*64, wc0 = (w & 1)*64;
  const int l15 = lane & 15, lg = lane >> 4;

  constexpr int CH = KIN/8;
  #pragma unroll
  for (int i = 0; i < (128*CH)/256; ++i){
    int chunk = tid + 256*i;
    int row = chunk / CH, kc = (chunk - row*CH)*8;
    const float* sp = Z + (size_t)(row0 + row)*KIN + kc;
    float4 a0 = *(const float4*)sp;
    float4 a1 = *(const float4*)(sp + 4);
    float vv[8] = {a0.x,a0.y,a0.z,a0.w,a1.x,a1.y,a1.z,a1.w};
    ushort8 vh, vl;
    #pragma unroll
    for (int q=0;q<8;++q){ unsigned short h = f2bf(vv[q]); vh[q]=h; vl[q]=f2bf(vv[q]-bf2f(h)); }
    *(ushort8*)&Ah[row*SA + kc] = vh;
    *(ushort8*)&Al[row*SA + kc] = vl;
  }
  __syncthreads();

  f32x4 acc[4][4];
  #pragma unroll
  for (int i=0;i<4;++i)
    #pragma unroll
    for (int j=0;j<4;++j) acc[i][j] = (f32x4)(0.0f);

  #pragma unroll
  for (int k0 = 0; k0 < KIN; k0 += 32){
    bf16x8 ah[4], al[4], bh[4], bl[4];
    #pragma unroll
    for (int fa=0; fa<4; ++fa){
      ah[fa] = *(const bf16x8*)&Ah[(wr + fa*16 + l15)*SA + k0 + 8*lg];
      al[fa] = *(const bf16x8*)&Al[(wr + fa*16 + l15)*SA + k0 + 8*lg];
    }
    #pragma unroll
    for (int fb=0; fb<4; ++fb){
      bh[fb] = *(const bf16x8*)&W1h[(wc0 + fb*16 + l15)*KIN + k0 + 8*lg];
      bl[fb] = *(const bf16x8*)&W1l[(wc0 + fb*16 + l15)*KIN + k0 + 8*lg];
    }
    #pragma unroll
    for (int fa=0; fa<4; ++fa)
      #pragma unroll
      for (int fb=0; fb<4; ++fb){
        acc[fa][fb] = __builtin_amdgcn_mfma_f32_16x16x32_bf16(ah[fa], bh[fb], acc[fa][fb], 0, 0, 0);
        acc[fa][fb] = __builtin_amdgcn_mfma_f32_16x16x32_bf16(al[fa], bh[fb], acc[fa][fb], 0, 0, 0);
        acc[fa][fb] = __builtin_amdgcn_mfma_f32_16x16x32_bf16(ah[fa], bl[fb], acc[fa][fb], 0, 0, 0);
      }
  }
  __syncthreads();

  {
    float b1v[4];
    #pragma unroll
    for (int fb=0; fb<4; ++fb) b1v[fb] = b1[wc0 + fb*16 + l15];
    #pragma unroll
    for (int fa=0; fa<4; ++fa)
      #pragma unroll
      for (int fb=0; fb<4; ++fb)
        #pragma unroll
        for (int r=0; r<4; ++r){
          float v = fmaxf(acc[fa][fb][r] + b1v[fb], 0.0f);
          unsigned short h = f2bf(v);
          int idx = (wr + fa*16 + lg*4 + r)*136 + (wc0 + fb*16 + l15);
          Ah[idx] = h;
          Al[idx] = f2bf(v - bf2f(h));
        }
  }
  __syncthreads();

  f32x4 acc2[4][4];
  #pragma unroll
  for (int i=0;i<4;++i)
    #pragma unroll
    for (int j=0;j<4;++j) acc2[i][j] = (f32x4)(0.0f);

  #pragma unroll
  for (int k0 = 0; k0 < 128; k0 += 32){
    bf16x8 ah[4], al[4], bh[4], bl[4];
    #pragma unroll
    for (int fa=0; fa<4; ++fa){
      ah[fa] = *(const bf16x8*)&Ah[(wr + fa*16 + l15)*136 + k0 + 8*lg];
      al[fa] = *(const bf16x8*)&Al[(wr + fa*16 + l15)*136 + k0 + 8*lg];
    }
    #pragma unroll
    for (int fb=0; fb<4; ++fb){
      bh[fb] = *(const bf16x8*)&W2h[(wc0 + fb*16 + l15)*128 + k0 + 8*lg];
      bl[fb] = *(const bf16x8*)&W2l[(wc0 + fb*16 + l15)*128 + k0 + 8*lg];
    }
    #pragma unroll
    for (int fa=0; fa<4; ++fa)
      #pragma unroll
      for (int fb=0; fb<4; ++fb){
        acc2[fa][fb] = __builtin_amdgcn_mfma_f32_16x16x32_bf16(ah[fa], bh[fb], acc2[fa][fb], 0, 0, 0);
        acc2[fa][fb] = __builtin_amdgcn_mfma_f32_16x16x32_bf16(al[fa], bh[fb], acc2[fa][fb], 0, 0, 0);
        acc2[fa][fb] = __builtin_amdgcn_mfma_f32_16x16x32_bf16(ah[fa], bl[fb], acc2[fa][fb], 0, 0, 0);
      }
  }

  float b2v[4]; int cc[4];
  #pragma unroll
  for (int fb=0; fb<4; ++fb){ cc[fb] = wc0 + fb*16 + l15; b2v[fb] = b2[cc[fb]]; }
  float ps[4] = {0,0,0,0}, pq[4] = {0,0,0,0};
  #pragma unroll
  for (int fa=0; fa<4; ++fa)
    #pragma unroll
    for (int fb=0; fb<4; ++fb)
      #pragma unroll
      for (int r=0; r<4; ++r){
        int row = row0 + wr + fa*16 + lg*4 + r;
        float v = fmaxf(acc2[fa][fb][r] + b2v[fb], 0.0f);
        if (row < NN){
          Y[(size_t)row*128 + cc[fb]] = v;
          ps[fb] += v; pq[fb] += v*v;
        }
      }
  #pragma unroll
  for (int fb=0; fb<4; ++fb){
    float s = ps[fb]; s += __shfl_xor(s, 16); s += __shfl_xor(s, 32);
    float q = pq[fb]; q += __shfl_xor(q, 16); q += __shfl_xor(q, 32);
    if (lane < 16){ atomicAdd(&stats[cc[fb]], s); atomicAdd(&stats[128 + cc[fb]], q); }
  }
}

// ======================= BN helpers =======================
__global__ void bn_finalize_k(const float* __restrict__ stats, const float* __restrict__ gamma,
                              const float* __restrict__ beta, float* __restrict__ sshift, int C, float invN){
  int c = blockIdx.x*blockDim.x + threadIdx.x; if (c >= C) return;
  float mean = stats[c]*invN;
  float var  = fmaxf(stats[C+c]*invN - mean*mean, 0.0f);
  float inv  = rsqrtf(var + 1e-5f);
  float sc   = gamma[c]*inv;
  sshift[c] = sc; sshift[C+c] = beta[c] - mean*sc;
}

// fused BN apply + per-graph pooling; h stored packed bf16 (2/uint) for the gather
__global__ __launch_bounds__(256) void bn_pool_k(const float* __restrict__ Y,
    const float* __restrict__ sshift, const int* __restrict__ gstart,
    unsigned int* __restrict__ Hbf, float* __restrict__ pool, int layer)
{
  int g = blockIdx.x*4 + (threadIdx.x >> 6);
  if (g >= NB) return;
  int lane = threadIdx.x & 63;
  int c0 = lane << 1;
  float sc0 = sshift[c0],     sc1 = sshift[c0+1];
  float sh0 = sshift[128+c0], sh1 = sshift[128+c0+1];
  int n0 = gstart[g], n1 = gstart[g+1];
  const float2* Yp = (const float2*)Y;
  float2 acc = make_float2(0.f, 0.f);
  for (int r = n0; r < n1; ++r){
    float2 y = Yp[(size_t)r*64 + lane];
    float hx = y.x*sc0 + sh0;
    float hy = y.y*sc1 + sh1;
    Hbf[(size_t)r*64 + lane] = (unsigned int)f2bf(hx) | ((unsigned int)f2bf(hy) << 16);
    acc.x += hx; acc.y += hy;
  }
  ((float2*)pool)[(size_t)g*320 + layer*64 + lane] = acc;
}

// ======================= LSTM =======================
// e2 layout: [t][b][64]
__global__ __launch_bounds__(256) void embed_k(const int* __restrict__ smi,
    const unsigned short* __restrict__ emb_bf, unsigned short* __restrict__ e2){
  int gid = blockIdx.x*256 + threadIdx.x;
  int tb = gid >> 4;
  if (tb >= TT*BPAD) return;
  int t = tb / BPAD, b = tb - t*BPAD;
  int k4 = (gid & 15) << 2;
  uint2 v = make_uint2(0u, 0u);
  if (b < NB){
    int tok = smi[b*TT + t];
    v = *(const uint2*)&emb_bf[tok*64 + k4];
  }
  *(uint2*)&e2[(size_t)tb*64 + k4] = v;
}

// One LSTM step: gates = [h|e_t] @ Wc2^T + bias; double-buffered LDS, 1 barrier/K-step.
// 1D grid of 480 with XCD-aware swizzle (measured-best configuration).
__global__ __launch_bounds__(256) void lstm_step_k(const unsigned short* __restrict__ hprev,
    unsigned short* __restrict__ hnext, float* __restrict__ cbuf,
    const unsigned short* __restrict__ e2, const unsigned short* __restrict__ Wc2,
    const float* __restrict__ biasc, int t, float* __restrict__ hfin)
{
  __shared__ __align__(16) unsigned short As[2][128*40];
  __shared__ __align__(16) unsigned short Bs[2][128*40];
  const int tid = threadIdx.x, lane = tid & 63, w = tid >> 6;
  const int bid = blockIdx.x;
  const int xcd = bid & 7, idx = bid >> 3;
  const int rt = xcd*3 + (idx % 3);
  const int jt = idx / 3;                    // j-tile of 32
  const int row0 = rt * 128;
  const int l15 = lane & 15, lg = lane >> 4;
  const int wr = (w >> 1)*64, wc0 = (w & 1)*64;

  const int srow = tid >> 2, skc = (tid & 3) << 3;
  const unsigned short* A0 = hprev + (size_t)(row0 + srow)*HID;
  const unsigned short* A1 = hprev + (size_t)(row0 + srow + 64)*HID;
  const unsigned short* E0 = e2 + ((size_t)t*BPAD + row0 + srow)*64;
  const unsigned short* E1 = e2 + ((size_t)t*BPAD + row0 + srow + 64)*64;
  const unsigned short* B0 = Wc2 + (size_t)(jt*128 + srow)*704;
  const unsigned short* B1 = Wc2 + (size_t)(jt*128 + srow + 64)*704;

  *(ushort8*)&As[0][srow*40 + skc]      = *(const ushort8*)&A0[skc];
  *(ushort8*)&As[0][(srow+64)*40 + skc] = *(const ushort8*)&A1[skc];
  *(ushort8*)&Bs[0][srow*40 + skc]      = *(const ushort8*)&B0[skc];
  *(ushort8*)&Bs[0][(srow+64)*40 + skc] = *(const ushort8*)&B1[skc];
  __syncthreads();

  f32x4 acc[4][4];
  #pragma unroll
  for (int i=0;i<4;++i)
    #pragma unroll
    for (int j=0;j<4;++j) acc[i][j] = (f32x4)(0.0f);

  int p = 0;
  for (int kk = 0; kk < 22; ++kk){
    ushort8 va0, va1, vb0, vb1;
    const int k1 = (kk+1)*32;
    if (kk < 21){
      if (k1 < 640){
        va0 = *(const ushort8*)&A0[k1 + skc];
        va1 = *(const ushort8*)&A1[k1 + skc];
      } else {
        va0 = *(const ushort8*)&E0[k1 - 640 + skc];
        va1 = *(const ushort8*)&E1[k1 - 640 + skc];
      }
      vb0 = *(const ushort8*)&B0[k1 + skc];
      vb1 = *(const ushort8*)&B1[k1 + skc];
    }
    bf16x8 a[4], b[4];
    #pragma unroll
    for (int fa=0; fa<4; ++fa) a[fa] = *(const bf16x8*)&As[p][(wr + fa*16 + l15)*40 + 8*lg];
    #pragma unroll
    for (int fb=0; fb<4; ++fb) b[fb] = *(const bf16x8*)&Bs[p][(wc0 + fb*16 + l15)*40 + 8*lg];
    __builtin_amdgcn_s_setprio(1);
    #pragma unroll
    for (int fa=0; fa<4; ++fa)
      #pragma unroll
      for (int fb=0; fb<4; ++fb)
        acc[fa][fb] = __builtin_amdgcn_mfma_f32_16x16x32_bf16(a[fa], b[fb], acc[fa][fb], 0, 0, 0);
    __builtin_amdgcn_s_setprio(0);
    if (kk < 21){
      *(ushort8*)&As[p^1][srow*40 + skc]      = va0;
      *(ushort8*)&As[p^1][(srow+64)*40 + skc] = va1;
      *(ushort8*)&Bs[p^1][srow*40 + skc]      = vb0;
      *(ushort8*)&Bs[p^1][(srow+64)*40 + skc] = vb1;
    }
    __syncthreads();
    p ^= 1;
  }

  const int j = jt*32 + (w & 1)*16 + l15;
  float bi = biasc[j], bf_ = biasc[640+j], bg = biasc[1280+j], bo = biasc[1920+j];
  #pragma unroll
  for (int fa=0; fa<4; ++fa){
    #pragma unroll
    for (int r=0; r<4; ++r){
      int br = row0 + wr + fa*16 + lg*4 + r;
      float iv = acc[fa][0][r] + bi;
      float fv = acc[fa][1][r] + bf_;
      float gv = acc[fa][2][r] + bg;
      float ov = acc[fa][3][r] + bo;
      size_t idx2 = (size_t)br*HID + j;
      float co = cbuf[idx2];
      float cn = sigf(fv)*co + sigf(iv)*tanhf_fast(gv);
      cbuf[idx2] = cn;
      float hv = sigf(ov)*tanhf_fast(cn);
      hnext[idx2] = f2bf(hv);
      if (hfin) hfin[idx2] = hv;
    }
  }
}

// ======================= split-precision GEMM (heads) =======================
template<int DO_STATS>
__global__ __launch_bounds__(256) void gemm_split_k(const float* __restrict__ A,
    const unsigned short* __restrict__ Bh, const unsigned short* __restrict__ Bl,
    const float* __restrict__ bias, float* __restrict__ outp, float* __restrict__ stats,
    int Mvalid, int Nc, int K)
{
  __shared__ __align__(16) unsigned short Ah[128*40];
  __shared__ __align__(16) unsigned short Al[128*40];
  const int tid = threadIdx.x, lane = tid & 63, w = tid >> 6;
  const int row0 = blockIdx.x * 128, col0 = blockIdx.y * 128;
  const int wr = (w >> 1)*64, wc0 = (w & 1)*64;
  const int l15 = lane & 15, lg = lane >> 4;

  f32x4 acc[4][4];
  #pragma unroll
  for (int i=0;i<4;++i)
    #pragma unroll
    for (int j=0;j<4;++j) acc[i][j] = (f32x4)(0.0f);

  for (int k0 = 0; k0 < K; k0 += 32){
    #pragma unroll
    for (int i=0;i<2;++i){
      int chunk = tid + 256*i;
      int row = chunk >> 2, kc = (chunk & 3) << 3;
      const float* sp = A + (size_t)(row0+row)*K + k0 + kc;
      float4 a0 = *(const float4*)sp;
      float4 a1 = *(const float4*)(sp + 4);
      float vv[8] = {a0.x,a0.y,a0.z,a0.w,a1.x,a1.y,a1.z,a1.w};
      ushort8 vh, vl;
      #pragma unroll
      for (int q=0;q<8;++q){ unsigned short h = f2bf(vv[q]); vh[q]=h; vl[q]=f2bf(vv[q]-bf2f(h)); }
      *(ushort8*)&Ah[row*40 + kc] = vh;
      *(ushort8*)&Al[row*40 + kc] = vl;
    }
    __syncthreads();
    bf16x8 ah[4], al[4], bh[4], bl[4];
    #pragma unroll
    for (int fa=0; fa<4; ++fa){
      ah[fa] = *(const bf16x8*)&Ah[(wr + fa*16 + l15)*40 + 8*lg];
      al[fa] = *(const bf16x8*)&Al[(wr + fa*16 + l15)*40 + 8*lg];
    }
    #pragma unroll
    for (int fb=0; fb<4; ++fb){
      bh[fb] = *(const bf16x8*)&Bh[(size_t)(col0 + wc0 + fb*16 + l15)*K + k0 + 8*lg];
      bl[fb] = *(const bf16x8*)&Bl[(size_t)(col0 + wc0 + fb*16 + l15)*K + k0 + 8*lg];
    }
    #pragma unroll
    for (int fa=0; fa<4; ++fa)
      #pragma unroll
      for (int fb=0; fb<4; ++fb){
        acc[fa][fb] = __builtin_amdgcn_mfma_f32_16x16x32_bf16(ah[fa], bh[fb], acc[fa][fb], 0, 0, 0);
        acc[fa][fb] = __builtin_amdgcn_mfma_f32_16x16x32_bf16(al[fa], bh[fb], acc[fa][fb], 0, 0, 0);
        acc[fa][fb] = __builtin_amdgcn_mfma_f32_16x16x32_bf16(ah[fa], bl[fb], acc[fa][fb], 0, 0, 0);
      }
    __syncthreads();
  }

  float bv[4]; int cc[4];
  #pragma unroll
  for (int fb=0; fb<4; ++fb){ cc[fb] = col0 + wc0 + fb*16 + l15; bv[fb] = bias ? bias[cc[fb]] : 0.0f; }
  float ps[4] = {0,0,0,0}, pq[4] = {0,0,0,0};
  #pragma unroll
  for (int fa=0; fa<4; ++fa)
    #pragma unroll
    for (int fb=0; fb<4; ++fb)
      #pragma unroll
      for (int r=0; r<4; ++r){
        int row = row0 + wr + fa*16 + lg*4 + r;
        float v = acc[fa][fb][r] + bv[fb];
        if (row < Mvalid){
          outp[(size_t)row*Nc + cc[fb]] = v;
          if (DO_STATS){ ps[fb] += v; pq[fb] += v*v; }
        }
      }
  if (DO_STATS){
    #pragma unroll
    for (int fb=0; fb<4; ++fb){
      float s = ps[fb]; s += __shfl_xor(s, 16); s += __shfl_xor(s, 32);
      float q = pq[fb]; q += __shfl_xor(q, 16); q += __shfl_xor(q, 32);
      if (lane < 16){ atomicAdd(&stats[cc[fb]], s); atomicAdd(&stats[Nc + cc[fb]], q); }
    }
  }
}

__global__ __launch_bounds__(256) void bn_apply_head_k(const float* __restrict__ Zpre,
    const float* __restrict__ sshift, float* __restrict__ z1f){
  int gid = blockIdx.x*256 + threadIdx.x;
  int r = gid >> 7;
  if (r >= BPAD) return;
  int c0 = (gid & 127) << 2;
  float4 o = make_float4(0.f,0.f,0.f,0.f);
  if (r < NB){
    float4 v = *(const float4*)&Zpre[(size_t)r*512 + c0];
    o.x = fmaxf(v.x*sshift[c0+0] + sshift[512+c0+0], 0.0f);
    o.y = fmaxf(v.y*sshift[c0+1] + sshift[512+c0+1], 0.0f);
    o.z = fmaxf(v.z*sshift[c0+2] + sshift[512+c0+2], 0.0f);
    o.w = fmaxf(v.w*sshift[c0+3] + sshift[512+c0+3], 0.0f);
  }
  *(float4*)&z1f[(size_t)r*512 + c0] = o;
}

__global__ __launch_bounds__(256) void rownorm_k(const float* __restrict__ in, float* __restrict__ outp){
  int r = blockIdx.x;
  const float* p = in + (size_t)r*768;
  float ss = 0.0f;
  #pragma unroll
  for (int i = 0; i < 3; ++i){ float v = p[threadIdx.x + 256*i]; ss += v*v; }
  #pragma unroll
  for (int m = 1; m < 64; m <<= 1) ss += __shfl_xor(ss, m);
  __shared__ float red[4];
  if ((threadIdx.x & 63) == 0) red[threadIdx.x >> 6] = ss;
  __syncthreads();
  float tot = red[0] + red[1] + red[2] + red[3];
  float inv = 1.0f / fmaxf(sqrtf(tot), 1e-12f);
  float* q = outp + (size_t)r*768;
  #pragma unroll
  for (int i = 0; i < 3; ++i) q[threadIdx.x + 256*i] = p[threadIdx.x + 256*i]*inv;
}

// ======================= launcher =======================
static inline int cdiv(long a, long b){ return (int)((a + b - 1)/b); }

extern "C" void kernel_launch(void* const* d_in, const int* in_sizes, int n_in,
                              void* d_out, int out_size, void* d_ws, size_t ws_size,
                              hipStream_t stream)
{
  const float* x        = (const float*)d_in[0];
  const int*   edges    = (const int*)d_in[1];
  const int*   batch    = (const int*)d_in[2];
  const int*   smi      = (const int*)d_in[3];
  const float* gin0_w1  = (const float*)d_in[4];
  const float* gin0_b1  = (const float*)d_in[5];
  const float* gin0_w2  = (const float*)d_in[6];
  const float* gin0_b2  = (const float*)d_in[7];
  const float* ginr_w1  = (const float*)d_in[8];
  const float* ginr_b1  = (const float*)d_in[9];
  const float* ginr_w2  = (const float*)d_in[10];
  const float* ginr_b2  = (const float*)d_in[11];
  const float* bn_gamma = (const float*)d_in[12];
  const float* bn_beta  = (const float*)d_in[13];
  const float* emb      = (const float*)d_in[14];
  const float* w_ih     = (const float*)d_in[15];
  const float* w_hh     = (const float*)d_in[16];
  const float* b_ih     = (const float*)d_in[17];
  const float* b_hh     = (const float*)d_in[18];
  const float* g_w1     = (const float*)d_in[19];
  const float* g_b1     = (const float*)d_in[20];
  const float* g_bng    = (const float*)d_in[21];
  const float* g_bnb    = (const float*)d_in[22];
  const float* g_w2     = (const float*)d_in[23];
  float* outp = (float*)d_out;
  const int* srcs = edges;
  const int* dsts = edges + NE;

  char* base = (char*)d_ws;
  size_t off = 0;
  auto carve = [&](size_t bytes)->char*{ char* p = base + off; off += (bytes + 255) & ~(size_t)255; return p; };
  float* z_gin = (float*)carve((size_t)NPAD*128*4);      // reused for head temps
  float* y_gin = (float*)carve((size_t)NPAD*128*4);      // reused for e2
  float* h_gin = (float*)carve((size_t)NPAD*128*4);      // h_bf (uint-packed bf16) + LSTM state
  float* pool  = (float*)carve((size_t)BPAD*HID*4);
  unsigned short* Wc2    = (unsigned short*)carve((size_t)2560*704*2);
  float*          biasc  = (float*)carve(2560*4);
  unsigned short* emb_bf = (unsigned short*)carve(4096*2);
  unsigned short* w1t0h  = (unsigned short*)carve(128*32*2);
  unsigned short* w1t0l  = (unsigned short*)carve(128*32*2);
  unsigned short* w2t0h  = (unsigned short*)carve(128*128*2);
  unsigned short* w2t0l  = (unsigned short*)carve(128*128*2);
  unsigned short* w1trh  = (unsigned short*)carve(4*16384*2);
  unsigned short* w1trl  = (unsigned short*)carve(4*16384*2);
  unsigned short* w2trh  = (unsigned short*)carve(4*16384*2);
  unsigned short* w2trl  = (unsigned short*)carve(4*16384*2);
  unsigned short* gw1th  = (unsigned short*)carve(512*640*2);
  unsigned short* gw1tl  = (unsigned short*)carve(512*640*2);
  unsigned short* gw2th  = (unsigned short*)carve(768*512*2);
  unsigned short* gw2tl  = (unsigned short*)carve(768*512*2);
  float* stats  = (float*)carve(1024*4);
  float* sshift = (float*)carve(1024*4);
  int* deg    = (int*)carve((size_t)NN*4);
  int* cursor = (int*)carve((size_t)NN*4);
  int* rowptr = (int*)carve((size_t)(NN+1)*4);
  int* bsum   = (int*)carve(512);
  int* eidx   = (int*)carve((size_t)NE*4);
  int* gstart = (int*)carve((size_t)(NB+1)*4);

  // aliases (regions free at the time of reuse)
  unsigned int*   h_bf   = (unsigned int*)h_gin;                         // [NN][64] packed 2xbf16, 25.6 MB
  unsigned short* e2     = (unsigned short*)y_gin;                       // [t][b][64], 50.3 MB
  unsigned short* h_a    = (unsigned short*)h_gin;
  unsigned short* h_b    = h_a + (size_t)BPAD*HID;
  float*          c_buf  = (float*)(h_b + (size_t)BPAD*HID);
  float*          hfin   = c_buf + (size_t)BPAD*HID;                     // fp32 final h
  float*          z1pre  = (float*)z_gin;
  float*          z1f    = z1pre + (size_t)BPAD*512;
  float*          outtmp = z1f + (size_t)BPAD*512;

  // ---- prep (weight conversions) ----
  wc2_build_k<<<cdiv((long)2560*704,256),256,0,stream>>>(w_hh, w_ih, Wc2);
  add_k<<<cdiv(2560,256),256,0,stream>>>(b_ih, b_hh, biasc, 2560);
  cvt_k<<<cdiv(4096,256),256,0,stream>>>(emb, emb_bf, 4096);
  transpose_cvt_split_k<<<cdiv(32*128,256),256,0,stream>>>(gin0_w1, w1t0h, w1t0l, 32, 128);
  transpose_cvt_split_k<<<cdiv(16384,256),256,0,stream>>>(gin0_w2, w2t0h, w2t0l, 128, 128);
  for (int i = 0; i < 4; ++i){
    transpose_cvt_split_k<<<cdiv(16384,256),256,0,stream>>>(ginr_w1 + (size_t)i*16384, w1trh + (size_t)i*16384, w1trl + (size_t)i*16384, 128, 128);
    transpose_cvt_split_k<<<cdiv(16384,256),256,0,stream>>>(ginr_w2 + (size_t)i*16384, w2trh + (size_t)i*16384, w2trl + (size_t)i*16384, 128, 128);
  }
  transpose_cvt_split_k<<<cdiv(640*512,256),256,0,stream>>>(g_w1, gw1th, gw1tl, 640, 512);
  transpose_cvt_split_k<<<cdiv(512*768,256),256,0,stream>>>(g_w2, gw2th, gw2tl, 512, 768);

  // ---- CSR + graph bounds (once) ----
  hipMemsetAsync(deg, 0, (size_t)NN*4, stream);
  deg_hist_k<<<cdiv(NE,256),256,0,stream>>>(dsts, deg);
  scan_bsum_k<<<NBLK,256,0,stream>>>(deg, bsum);
  scan_off_k<<<1,64,0,stream>>>(bsum);
  scan_write_k<<<NBLK,256,0,stream>>>(deg, bsum, rowptr, cursor);
  csr_fill_k<<<cdiv(NE,256),256,0,stream>>>(srcs, dsts, cursor, eidx);
  gbound_k<<<cdiv(NN,256),256,0,stream>>>(batch, gstart);

  // ---- GIN encoder ----
  for (int l = 0; l < 5; ++l){
    hipMemsetAsync(stats, 0, 1024*4, stream);
    if (l == 0)
      agg32_k<<<cdiv((long)NN*32,256),256,0,stream>>>(rowptr, eidx, x, z_gin);
    else
      agg128_k<<<cdiv((long)NN*64,256),256,0,stream>>>(rowptr, eidx, h_bf, z_gin);
    if (l == 0)
      gin_mlp_k<32><<<NPAD/128,256,0,stream>>>(z_gin, w1t0h, w1t0l, w2t0h, w2t0l, gin0_b1, gin0_b2, y_gin, stats);
    else
      gin_mlp_k<128><<<NPAD/128,256,0,stream>>>(z_gin, w1trh + (size_t)(l-1)*16384, w1trl + (size_t)(l-1)*16384,
                                                w2trh + (size_t)(l-1)*16384, w2trl + (size_t)(l-1)*16384,
                                                ginr_b1 + (l-1)*128, ginr_b2 + (l-1)*128, y_gin, stats);
    bn_finalize_k<<<1,128,0,stream>>>(stats, bn_gamma + l*128, bn_beta + l*128, sshift, 128, 1.0f/NN);
    bn_pool_k<<<cdiv(NB,4),256,0,stream>>>(y_gin, sshift, gstart, h_bf, pool, l);
  }

  // ---- LSTM (per-step launches; XCD-swizzled 1D grid of 480) ----
  embed_k<<<cdiv((long)TT*BPAD*16,256),256,0,stream>>>(smi, emb_bf, e2);
  hipMemsetAsync(h_a, 0, (size_t)BPAD*HID*2, stream);
  hipMemsetAsync(c_buf, 0, (size_t)BPAD*HID*4, stream);
  for (int t = 0; t < TT; ++t){
    const unsigned short* hin = (t & 1) ? h_b : h_a;
    unsigned short* hout      = (t & 1) ? h_a : h_b;
    lstm_step_k<<<480,256,0,stream>>>(hin, hout, c_buf, e2, Wc2, biasc, t,
                                      (t == TT-1) ? hfin : nullptr);
  }

  // ---- heads ----
  const float* headAf[2] = { pool, hfin };
  for (int hd = 0; hd < 2; ++hd){
    hipMemsetAsync(stats, 0, 1024*4, stream);
    gemm_split_k<1><<<dim3(BPAD/128, 4),256,0,stream>>>(headAf[hd], gw1th, gw1tl, g_b1, z1pre, stats, NB, 512, 640);
    bn_finalize_k<<<2,256,0,stream>>>(stats, g_bng, g_bnb, sshift, 512, 1.0f/NB);
    bn_apply_head_k<<<cdiv((long)BPAD*128,256),256,0,stream>>>(z1pre, sshift, z1f);
    gemm_split_k<0><<<dim3(BPAD/128, 6),256,0,stream>>>(z1f, gw2th, gw2tl, nullptr, outtmp, nullptr, NB, 768, 512);
    rownorm_k<<<NB,256,0,stream>>>(outtmp, outp + (size_t)hd*NB*768);
  }
}